// Round 7
// baseline (549.436 us; speedup 1.0000x reference)
//
#include <hip/hip_runtime.h>
#include <hip/hip_bf16.h>
#include <math.h>

#define D 64
#define RU 256
#define CHUNK 8
#define QSTRIDE 68
#define BIN_SHIFT 7          // 128 links per coarse bin
#define NSB 128              // setup blocks for histA/scatterC

#if __has_builtin(__builtin_amdgcn_exp2f)
#define EXP2F(x) __builtin_amdgcn_exp2f(x)
#else
#define EXP2F(x) exp2f(x)
#endif

typedef short bf16x8 __attribute__((ext_vector_type(8)));
typedef float f32x4 __attribute__((ext_vector_type(4)));
typedef float f32x2 __attribute__((ext_vector_type(2)));

__device__ __forceinline__ float selu_f(float x) {
    return x > 0.0f ? 1.0507009873554805f * x
                    : 1.7580993408473766f * (__expf(x) - 1.0f);
}

// pair selu on pre-scaled input (x2 = log2e*x), packed-FP32 friendly:
// selu = 1.7581*exp2(min(x2,0)) + (1.0507*ln2)*max(x2,0) - 1.7581
__device__ __forceinline__ f32x2 selu_pair(f32x2 x) {
    const f32x2 z = {0.0f, 0.0f};
    const f32x2 p = __builtin_elementwise_max(x, z);
    const f32x2 n = __builtin_elementwise_min(x, z);
    f32x2 e;
    e.x = EXP2F(n.x);
    e.y = EXP2F(n.y);
    const f32x2 c1 = {1.7580993408473766f, 1.7580993408473766f};
    const f32x2 c2 = {0.72829042516f, 0.72829042516f};
    const f32x2 c3 = {-1.7580993408473766f, -1.7580993408473766f};
    return c1 * e + (c2 * p + c3);     // -ffp-contract -> v_pk_fma_f32
}

__device__ __forceinline__ short f2bf_rtne(float x) {
    union { float f; unsigned u; } v; v.f = x;
    unsigned r = (v.u + 0x7FFFu + ((v.u >> 16) & 1u)) >> 16;
    return (short)r;
}
__device__ __forceinline__ float bf2f(short s) {
    union { float f; unsigned u; } v; v.u = ((unsigned)(unsigned short)s) << 16;
    return v.f;
}
__device__ __forceinline__ float u2f(unsigned u) {
    union { float f; unsigned u; } v; v.u = u;
    return v.f;
}
__device__ __forceinline__ unsigned packpair(float a, float b) {
    float2 p; p.x = a; p.y = b;
    __hip_bfloat162 hb = __float22bfloat162_rn(p);
    return *(unsigned*)&hb;
}

// fragment layout index: element i of the (ks,jt) B-fragment for lane (qd,m)
#define FIDX(ks, jt, qd, m) ((((((ks) * 4 + (jt)) * 4 + (qd)) * 16) + (m)) * 8)

// ================= one-shot weight fragment prep (fp32 -> bf16 hi/lo) =======
// Also: sentinel P row (bf16 -inf) + cstar[col] = relu(b + c0*colsum(Wgcn_bf16))
__global__ __launch_bounds__(256) void wprep_kernel(
    const float* __restrict__ W_msg, const float* __restrict__ W_gcn,
    const float* __restrict__ b_gcn,
    unsigned short* __restrict__ WAh, unsigned short* __restrict__ WAl,
    unsigned short* __restrict__ WBh, unsigned short* __restrict__ WBl,
    unsigned short* __restrict__ WGh, float* __restrict__ cstar,
    unsigned short* __restrict__ Pb, int n_links)
{
    const float LOG2E = 1.4426950408889634f;
    const int t = blockIdx.x * 256 + threadIdx.x;

    if (blockIdx.x == 0 && threadIdx.x < 64) {
        const int col = threadIdx.x;
        Pb[(size_t)n_links * 64 + col] = 0xFF80;   // bf16 -inf sentinel row
        const float c0 = bf2f(f2bf_rtne(-1.7580993408473766f));
        float acc = b_gcn[col];
        for (int k = 0; k < 64; ++k)
            acc = fmaf(c0, bf2f(f2bf_rtne(W_gcn[k * 64 + col])), acc);
        cstar[col] = fmaxf(acc, 0.0f);
    }

    if (t >= 4096) return;
    const int i  = t & 7;
    const int m  = (t >> 3) & 15;
    const int qd = (t >> 7) & 3;
    const int jt = (t >> 9) & 3;
    const int ks = t >> 11;
    const int kk = ks * 32 + qd * 8 + i;
    const int nn = jt * 16 + m;

    float w = W_msg[kk * 64 + nn] * LOG2E;
    short hi = f2bf_rtne(w);
    WAh[t] = (unsigned short)hi;
    WAl[t] = (unsigned short)f2bf_rtne(w - bf2f(hi));

    w = W_msg[(64 + kk) * 64 + nn] * LOG2E;
    hi = f2bf_rtne(w);
    WBh[t] = (unsigned short)hi;
    WBl[t] = (unsigned short)f2bf_rtne(w - bf2f(hi));

    WGh[t] = (unsigned short)f2bf_rtne(W_gcn[kk * 64 + nn]);
}

// ================= input conversion: fp32 state -> bf16 =================
__global__ __launch_bounds__(256) void s2bf_kernel(
    const float* __restrict__ in, unsigned short* __restrict__ out, int n4)
{
    for (int i = blockIdx.x * 256 + threadIdx.x; i < n4; i += gridDim.x * 256) {
        const float4 v = ((const float4*)in)[i];
        uint2 o;
        o.x = packpair(v.x, v.y);
        o.y = packpair(v.z, v.w);
        ((uint2*)out)[i] = o;
    }
}

// ================= atomic-free CSR build (hierarchical scans) ===============

__global__ __launch_bounds__(256) void histA_kernel(
    const int* __restrict__ second, int* __restrict__ ghist,
    int n_edges, int nbins)
{
    __shared__ int lhist[1024];
    for (int i = threadIdx.x; i < nbins; i += 256) lhist[i] = 0;
    __syncthreads();
    const int per = (n_edges + gridDim.x - 1) / gridDim.x;
    const int e0 = blockIdx.x * per;
    const int e1 = min(e0 + per, n_edges);
    for (int e = e0 + threadIdx.x; e < e1; e += 256)
        atomicAdd(&lhist[second[e] >> BIN_SHIFT], 1);
    __syncthreads();
    for (int i = threadIdx.x; i < nbins; i += 256)
        ghist[i * gridDim.x + blockIdx.x] = lhist[i];
}

// per-bin: exclusive scan of the NSB=128 per-block counters (in place) + bin total
__global__ __launch_bounds__(64) void sumbins_kernel(
    int* __restrict__ ghist, int* __restrict__ btot, int nbins)
{
    const int b = blockIdx.x, tid = threadIdx.x;
    const int d0 = ghist[b * NSB + tid];
    const int d1 = ghist[b * NSB + 64 + tid];
    int p0 = d0, p1 = d1;
#pragma unroll
    for (int off = 1; off < 64; off <<= 1) {
        const int t0 = __shfl_up(p0, off, 64);
        const int t1 = __shfl_up(p1, off, 64);
        if (tid >= off) { p0 += t0; p1 += t1; }
    }
    const int tot0 = __shfl(p0, 63, 64);
    ghist[b * NSB + tid] = p0 - d0;
    ghist[b * NSB + 64 + tid] = tot0 + p1 - d1;
    if (tid == 63) btot[b] = tot0 + p1;
}

// single-block exclusive scan, n <= 1024, in place
__global__ __launch_bounds__(1024) void scanS_kernel(int* __restrict__ data, int n)
{
    __shared__ int wsum[16], woff[16];
    const int tid = threadIdx.x, wave = tid >> 6, lane = tid & 63;
    const int x = (tid < n) ? data[tid] : 0;
    int v = x;
#pragma unroll
    for (int off = 1; off < 64; off <<= 1) {
        const int t = __shfl_up(v, off, 64);
        if (lane >= off) v += t;
    }
    if (lane == 63) wsum[wave] = v;
    __syncthreads();
    if (wave == 0) {
        int s = (lane < 16) ? wsum[lane] : 0;
#pragma unroll
        for (int off = 1; off < 16; off <<= 1) {
            const int t = __shfl_up(s, off, 64);
            if (lane >= off) s += t;
        }
        if (lane < 16) woff[lane] = s - wsum[lane];
    }
    __syncthreads();
    if (tid < n) data[tid] = woff[wave] + v - x;
}

// packed tmp: bits [0,20) = first, bits [20,27) = second & 127
__global__ __launch_bounds__(256) void scatterC_kernel(
    const int* __restrict__ first, const int* __restrict__ second,
    const int* __restrict__ ghist, const int* __restrict__ btot,
    unsigned* __restrict__ tmp, int n_edges, int nbins)
{
    __shared__ int lcur[1024];
    for (int i = threadIdx.x; i < nbins; i += 256)
        lcur[i] = ghist[i * NSB + blockIdx.x] + btot[i];
    __syncthreads();
    const int per = (n_edges + gridDim.x - 1) / gridDim.x;
    const int e0 = blockIdx.x * per;
    const int e1 = min(e0 + per, n_edges);
    for (int e = e0 + threadIdx.x; e < e1; e += 256) {
        const int s = second[e];
        const int pos = atomicAdd(&lcur[s >> BIN_SHIFT], 1);
        tmp[pos] = (unsigned)first[e] | ((unsigned)(s & 127) << 20);
    }
}

__global__ __launch_bounds__(256) void binsortD_kernel(
    const unsigned* __restrict__ tmp, const int* __restrict__ btot,
    int* __restrict__ sfirst, int* __restrict__ row_ptr, int* __restrict__ ptot,
    int n_edges, int n_links, int nbins)
{
    __shared__ int ldeg[128];
    __shared__ int lpre[128];
    __shared__ int lcur[128];
    const int b = blockIdx.x;
    const int tid = threadIdx.x;
    const int lbase = b << BIN_SHIFT;
    const int nl = min(128, n_links - lbase);
    const int eb = btot[b];
    const int ee = (b + 1 < nbins) ? btot[b + 1] : n_edges;

    if (tid < 128) ldeg[tid] = 0;
    __syncthreads();
    for (int e = eb + tid; e < ee; e += 256)
        atomicAdd(&ldeg[tmp[e] >> 20], 1);
    __syncthreads();
    if (tid < 64) {
        const int d0 = ldeg[tid], d1 = ldeg[64 + tid];
        int p0 = d0, p1 = d1;
#pragma unroll
        for (int off = 1; off < 64; off <<= 1) {
            const int t0 = __shfl_up(p0, off, 64);
            const int t1 = __shfl_up(p1, off, 64);
            if (tid >= off) { p0 += t0; p1 += t1; }
        }
        const int tot0 = __shfl(p0, 63, 64);
        lpre[tid] = p0 - d0;
        lpre[64 + tid] = tot0 + p1 - d1;
        // padded tile-count total for this bin
        const int n0 = (d0 + 15) >> 4, n1 = (d1 + 15) >> 4;
        int q0 = n0, q1 = n1;
#pragma unroll
        for (int off = 1; off < 64; off <<= 1) {
            const int t0 = __shfl_up(q0, off, 64);
            const int t1 = __shfl_up(q1, off, 64);
            if (tid >= off) { q0 += t0; q1 += t1; }
        }
        if (tid == 63) ptot[b] = q0 + q1;
    }
    __syncthreads();
    if (tid < nl) row_ptr[lbase + tid] = eb + lpre[tid];
    if (b == nbins - 1 && tid == 0) row_ptr[n_links] = n_edges;
    if (tid < 128) lcur[tid] = lpre[tid];
    __syncthreads();
    for (int e = eb + tid; e < ee; e += 256) {
        const unsigned v = tmp[e];
        const int pos = eb + atomicAdd(&lcur[v >> 20], 1);
        sfirst[pos] = (int)(v & 0xFFFFFu);
    }
    if (b == 0)
        for (int i = tid; i < 64; i += 256) sfirst[n_edges + i] = 0;  // pipeline pad
}

// build per-tile descriptors: tinfo[t] = eo | li<<21 | last<<24 | vcnt<<25
// and per-link tile prefix ptile[l] (ptile[n_links] = total tiles)
// NOTE: tinfo aliases the (dead-after-binsortD) tmp buffer.
__global__ __launch_bounds__(256) void tbuild_kernel(
    const int* __restrict__ row_ptr, const int* __restrict__ tbase,
    int* __restrict__ ptile, int* __restrict__ tinfo,
    int n_links, int nbins)
{
    __shared__ int rpl[130];
    __shared__ int ltp[130];
    const int b = blockIdx.x, tid = threadIdx.x;
    const int lbase = b << BIN_SHIFT;
    const int nl = min(128, n_links - lbase);
    if (tid <= nl) rpl[tid] = row_ptr[lbase + tid];
    __syncthreads();
    if (tid < 64) {
        const int d0 = (tid < nl) ? rpl[tid + 1] - rpl[tid] : 0;
        const int d1 = (64 + tid < nl) ? rpl[64 + tid + 1] - rpl[64 + tid] : 0;
        const int n0 = (d0 + 15) >> 4, n1 = (d1 + 15) >> 4;
        int p0 = n0, p1 = n1;
#pragma unroll
        for (int off = 1; off < 64; off <<= 1) {
            const int t0 = __shfl_up(p0, off, 64);
            const int t1 = __shfl_up(p1, off, 64);
            if (tid >= off) { p0 += t0; p1 += t1; }
        }
        const int tot0 = __shfl(p0, 63, 64);
        ltp[tid] = p0 - n0;
        ltp[64 + tid] = tot0 + p1 - n1;
        if (tid == 63) ltp[128] = tot0 + p1;
    }
    __syncthreads();
    const int tb = tbase[b];
    if (tid <= nl) ptile[lbase + tid] = tb + ltp[tid];
    const int ntb = ltp[128];
    for (int tl = tid; tl < ntb; tl += 256) {
        int lo = 0, hi = nl - 1;
        while (lo < hi) {                      // largest li with ltp[li] <= tl
            const int mid = (lo + hi + 1) >> 1;
            if (ltp[mid] <= tl) lo = mid; else hi = mid - 1;
        }
        const int li = lo;
        const int eo = rpl[li] + ((tl - ltp[li]) << 4);
        const int rend = rpl[li + 1];
        const int vc = min(16, rend - eo);
        const int last = (eo + 16 >= rend) ? 1 : 0;
        tinfo[tb + tl] = eo | ((li & 7) << 21) | (last << 24) | (vc << 25);
    }
    if (b == nbins - 1 && tid < 8) tinfo[tb + ntb + tid] = 0;  // SENT pads (vcnt=0)
}

__global__ __launch_bounds__(256) void growfind_kernel(
    const int* __restrict__ gid, int* __restrict__ grow, int n_links, int G)
{
    const int g = blockIdx.x * blockDim.x + threadIdx.x;
    if (g > G) return;
    if (g == G) { grow[G] = n_links; return; }
    int lo = 0, hi = n_links;
    while (lo < hi) {
        const int mid = (lo + hi) >> 1;
        if (gid[mid] < g) lo = mid + 1; else hi = mid;
    }
    grow[g] = lo;
}

// ---------------- P via MFMA: bf16 state A (direct loads), split-B ----------
__global__ __launch_bounds__(256) void p_mfma_kernel(
    const unsigned short* __restrict__ Sb,
    const unsigned short* __restrict__ WAh, const unsigned short* __restrict__ WAl,
    unsigned short* __restrict__ P, int n_links)
{
    const int tid = threadIdx.x;
    const int wave = tid >> 6;
    const int lane = tid & 63;
    const int m = lane & 15;
    const int qd = lane >> 4;

    bf16x8 Bh[2][4], Bl[2][4];
#pragma unroll
    for (int ks = 0; ks < 2; ++ks)
#pragma unroll
        for (int jt = 0; jt < 4; ++jt) {
            const int off = FIDX(ks, jt, qd, m);
            Bh[ks][jt] = *(const bf16x8*)(WAh + off);
            Bl[ks][jt] = *(const bf16x8*)(WAl + off);
        }
    const bf16x8 z = (bf16x8){0, 0, 0, 0, 0, 0, 0, 0};

    const int ngroups = (n_links + 63) >> 6;
    for (int g = blockIdx.x; g < ngroups; g += gridDim.x) {
        const int base = g * 64 + wave * 16;
        const int l = base + m;
        bf16x8 Ah0 = z, Ah1 = z;
        if (l < n_links) {
            Ah0 = *(const bf16x8*)(Sb + (size_t)l * D + qd * 8);
            Ah1 = *(const bf16x8*)(Sb + (size_t)l * D + 32 + qd * 8);
        }
        f32x4 accP[4];
#pragma unroll
        for (int jt = 0; jt < 4; ++jt) {
            accP[jt] = (f32x4){0.f, 0.f, 0.f, 0.f};
            accP[jt] = __builtin_amdgcn_mfma_f32_16x16x32_bf16(Ah0, Bh[0][jt], accP[jt], 0, 0, 0);
            accP[jt] = __builtin_amdgcn_mfma_f32_16x16x32_bf16(Ah0, Bl[0][jt], accP[jt], 0, 0, 0);
            accP[jt] = __builtin_amdgcn_mfma_f32_16x16x32_bf16(Ah1, Bh[1][jt], accP[jt], 0, 0, 0);
            accP[jt] = __builtin_amdgcn_mfma_f32_16x16x32_bf16(Ah1, Bl[1][jt], accP[jt], 0, 0, 0);
        }
#pragma unroll
        for (int r = 0; r < 4; ++r) {
            const int lr = base + qd * 4 + r;
            if (lr < n_links) {
#pragma unroll
                for (int jt = 0; jt < 4; ++jt)
                    P[(size_t)lr * D + jt * 16 + m] =
                        (unsigned short)f2bf_rtne(accP[jt][r]);
            }
        }
    }
}

// ---------------- link-centric fused edge kernel (tinfo-driven) -------------
// Round 6: packed-FP32 (VOP3P) elementwise path. selu + P+Q add + relu-accum
// restructured over f32x2 pairs -> v_pk_add/max/min/fma_f32 (gfx90a+ dual
// fp32 pipe). Neutral if backend scalarizes (same op count as round 5).
// Keeps (256,4) GPR cap (round-5 win: 4 waves/SIMD, no spill).
__global__ __launch_bounds__(256, 4) void edge_link_kernel(
    unsigned short* __restrict__ Sb, const unsigned short* __restrict__ P,
    const int* __restrict__ sfirst, const int* __restrict__ tinfo,
    const int* __restrict__ ptile,
    const float* __restrict__ b_msg,
    const unsigned short* __restrict__ WBh, const unsigned short* __restrict__ WBl,
    const unsigned short* __restrict__ WGh,
    const float* __restrict__ b_gcn, const float* __restrict__ cstar,
    int n_links)
{
    __shared__ float qt[4][CHUNK * QSTRIDE + 4];
    __shared__ float cbl[64];
    const int tid = threadIdx.x;
    const int wave = tid >> 6;
    const int lane = tid & 63;
    const int m = lane & 15;
    const int qd = lane >> 4;

    // each wave writes the full cbl (benign identical-value race across waves)
    cbl[lane] = cstar[lane];

    const int l0 = (blockIdx.x * 4 + wave) * CHUNK;
    if (l0 >= n_links) return;
    const int nl = min(CHUNK, n_links - l0);

    const float LOG2E = 1.4426950408889634f;
    float bmsgC[4];
#pragma unroll
    for (int jt = 0; jt < 4; ++jt) bmsgC[jt] = b_msg[jt * 16 + m] * LOG2E;

    // ---- Phase 1: Q-tile from bf16 state chunk (A direct, pre-split B) ----
    {
        const bf16x8 z = (bf16x8){0, 0, 0, 0, 0, 0, 0, 0};
        const int l = l0 + m;
        bf16x8 Ah0 = z, Ah1 = z;
        if ((l < n_links) && (m < CHUNK)) {
            Ah0 = *(const bf16x8*)(Sb + (size_t)l * D + qd * 8);
            Ah1 = *(const bf16x8*)(Sb + (size_t)l * D + 32 + qd * 8);
        }
        f32x4 accQ[4];
#pragma unroll
        for (int jt = 0; jt < 4; ++jt) accQ[jt] = (f32x4){0.f, 0.f, 0.f, 0.f};
#pragma unroll
        for (int ks = 0; ks < 2; ++ks) {
            bf16x8 WbH[4], WbL[4];
#pragma unroll
            for (int jt = 0; jt < 4; ++jt) {
                const int off = FIDX(ks, jt, qd, m);
                WbH[jt] = *(const bf16x8*)(WBh + off);
                WbL[jt] = *(const bf16x8*)(WBl + off);
            }
            const bf16x8 A = ks ? Ah1 : Ah0;
#pragma unroll
            for (int jt = 0; jt < 4; ++jt) {
                accQ[jt] = __builtin_amdgcn_mfma_f32_16x16x32_bf16(A, WbH[jt], accQ[jt], 0, 0, 0);
                accQ[jt] = __builtin_amdgcn_mfma_f32_16x16x32_bf16(A, WbL[jt], accQ[jt], 0, 0, 0);
            }
        }
#pragma unroll
        for (int r = 0; r < 4; ++r) {
            const int row = qd * 4 + r;
            if (row < CHUNK) {
#pragma unroll
                for (int jt = 0; jt < 4; ++jt)
                    qt[wave][row * QSTRIDE + jt * 16 + m] = accQ[jt][r] + bmsgC[jt];
            }
        }
    }

    // ---- W_gcn B-frags + scalar bias ----
    bf16x8 Gh[2][4];
#pragma unroll
    for (int ks = 0; ks < 2; ++ks)
#pragma unroll
        for (int jt = 0; jt < 4; ++jt)
            Gh[ks][jt] = *(const bf16x8*)(WGh + FIDX(ks, jt, qd, m));

    float bias_gcn[4];
#pragma unroll
    for (int jt = 0; jt < 4; ++jt) bias_gcn[jt] = b_gcn[jt * 16 + m];

    // ---- tile range for this chunk + zero empty links ----
    const int tpv = ptile[l0 + min(lane, nl)];
#pragma unroll
    for (int i = 0; i < CHUNK; ++i) {
        if (i < nl && __shfl(tpv, i + 1, 64) == __shfl(tpv, i, 64))
            Sb[(size_t)(l0 + i) * D + lane] = 0;
    }
    const int tbeg = __builtin_amdgcn_readfirstlane(tpv);
    const int tend = __builtin_amdgcn_readfirstlane(__shfl(tpv, nl, 64));
    if (tbeg >= tend) return;

    // ---- pipeline prologue: tinfo 3 deep, sf 1 deep, p current ----
    int ti0 = tinfo[tbeg];
    int ti1 = tinfo[tbeg + 1];
    int ti2 = tinfo[tbeg + 2];

    bf16x8 p00, p01;
    {
        const int eo = ti0 & 0x1FFFFF, vc = (ti0 >> 25) & 31;
        int sf = sfirst[eo + m];
        sf = (m < vc) ? sf : n_links;
        const unsigned short* Pr = P + (size_t)sf * D;
        p00 = *(const bf16x8*)(Pr + qd * 8);
        p01 = *(const bf16x8*)(Pr + 32 + qd * 8);
    }
    int sf1;
    {
        const int eo = ti1 & 0x1FFFFF, vc = (ti1 >> 25) & 31;
        int sf = sfirst[eo + m];
        sf1 = (m < vc) ? sf : n_links;
    }

    f32x2 rsum2[4];
#pragma unroll
    for (int jt = 0; jt < 4; ++jt) rsum2[jt] = (f32x2){0.f, 0.f};

    for (int t = tbeg; t < tend; ++t) {
        const int tiN = tinfo[t + 3];                 // padded past global end
        // sf for t+2
        const int eo2 = ti2 & 0x1FFFFF, vc2 = (ti2 >> 25) & 31;
        int sf2 = sfirst[eo2 + m];
        sf2 = (m < vc2) ? sf2 : n_links;
        // p for t+1
        const unsigned short* Pr1 = P + (size_t)sf1 * D;
        const bf16x8 p10 = *(const bf16x8*)(Pr1 + qd * 8);
        const bf16x8 p11 = *(const bf16x8*)(Pr1 + 32 + qd * 8);

        const int li0 = (ti0 >> 21) & 7;
        const int vc0 = (ti0 >> 25) & 31;
        const int qoff = li0 * QSTRIDE + qd * 8;

        // half A: qt re-read (2 x float4), pair selu (packed f32), pack
        bf16x8 Ah0, Ah1;
        {
            const float4 qa0 = *(const float4*)&qt[wave][qoff];
            const float4 qa1 = *(const float4*)&qt[wave][qoff + 4];
            union { bf16x8 v; unsigned u[4]; } U; U.v = p00;
            union { bf16x8 v; unsigned u[4]; } H;
#pragma unroll
            for (int j = 0; j < 4; ++j) {
                const unsigned u = U.u[j];
                f32x2 pv;
                pv.x = u2f(u << 16);
                pv.y = u2f(u & 0xFFFF0000u);
                f32x2 q;
                if (j < 2) { q.x = qa0[2 * j]; q.y = qa0[2 * j + 1]; }
                else       { q.x = qa1[2 * j - 4]; q.y = qa1[2 * j - 3]; }
                const f32x2 r = selu_pair(pv + q);
                H.u[j] = packpair(r.x, r.y);
            }
            Ah0 = H.v;
        }
        {
            const float4 qb0 = *(const float4*)&qt[wave][qoff + 32];
            const float4 qb1 = *(const float4*)&qt[wave][qoff + 36];
            union { bf16x8 v; unsigned u[4]; } U; U.v = p01;
            union { bf16x8 v; unsigned u[4]; } H;
#pragma unroll
            for (int j = 0; j < 4; ++j) {
                const unsigned u = U.u[j];
                f32x2 pv;
                pv.x = u2f(u << 16);
                pv.y = u2f(u & 0xFFFF0000u);
                f32x2 q;
                if (j < 2) { q.x = qb0[2 * j]; q.y = qb0[2 * j + 1]; }
                else       { q.x = qb1[2 * j - 4]; q.y = qb1[2 * j - 3]; }
                const f32x2 r = selu_pair(pv + q);
                H.u[j] = packpair(r.x, r.y);
            }
            Ah1 = H.v;
        }

        f32x4 acc[4];
#pragma unroll
        for (int jt = 0; jt < 4; ++jt) {
            const float b = bias_gcn[jt];
            acc[jt] = (f32x4){b, b, b, b};
            acc[jt] = __builtin_amdgcn_mfma_f32_16x16x32_bf16(Ah0, Gh[0][jt], acc[jt], 0, 0, 0);
            acc[jt] = __builtin_amdgcn_mfma_f32_16x16x32_bf16(Ah1, Gh[1][jt], acc[jt], 0, 0, 0);
        }
        // packed relu-accumulate: 2x v_pk_max + 2x v_pk_add per jt
        const f32x2 z2 = {0.f, 0.f};
#pragma unroll
        for (int jt = 0; jt < 4; ++jt) {
            const f32x2 lo = __builtin_shufflevector(acc[jt], acc[jt], 0, 1);
            const f32x2 hi = __builtin_shufflevector(acc[jt], acc[jt], 2, 3);
            rsum2[jt] += __builtin_elementwise_max(lo, z2)
                       + __builtin_elementwise_max(hi, z2);
        }

        if (ti0 & (1 << 24)) {                        // last tile of link li0
            const int over = qd * 4 + 4 - vc0;        // invalid rows in this qd group
            const float cnt = (float)max(0, min(4, over));
            float rsum[4];
#pragma unroll
            for (int jt = 0; jt < 4; ++jt) {
                rsum[jt] = rsum2[jt].x + rsum2[jt].y - cbl[jt * 16 + m] * cnt;
                rsum[jt] += __shfl_xor(rsum[jt], 16, 64);
                rsum[jt] += __shfl_xor(rsum[jt], 32, 64);
                rsum2[jt] = (f32x2){0.f, 0.f};
            }
            const float outv = (qd == 0) ? rsum[0] : (qd == 1) ? rsum[1]
                             : (qd == 2) ? rsum[2] : rsum[3];
            Sb[(size_t)(l0 + li0) * D + lane] = (unsigned short)f2bf_rtne(outv);
        }

        ti0 = ti1; ti1 = ti2; ti2 = tiN;
        sf1 = sf2;
        p00 = p10; p01 = p11;
    }
}

// ---------------- readout: parallel segment-sum (bf16 S) + tiny MLP ---------
__global__ __launch_bounds__(256) void gsum8_kernel(
    const unsigned short* __restrict__ Sb, const int* __restrict__ grow,
    float* __restrict__ gemb)
{
    __shared__ float red[4][64];
    const int g = blockIdx.x >> 3;
    const int slice = blockIdx.x & 7;
    const int slot = threadIdx.x >> 6;
    const int j = threadIdx.x & 63;
    const int ls = grow[g], le = grow[g + 1];
    float acc = 0.0f;
    for (int l = ls + slice * 4 + slot; l < le; l += 32)
        acc += bf2f((short)Sb[(size_t)l * D + j]);
    red[slot][j] = acc;
    __syncthreads();
    if (slot == 0)
        atomicAdd(&gemb[g * D + j], red[0][j] + red[1][j] + red[2][j] + red[3][j]);
}

__global__ __launch_bounds__(256) void mlp_kernel(
    const float* __restrict__ gemb,
    const float* __restrict__ W_r1, const float* __restrict__ b_r1,
    const float* __restrict__ W_r2, const float* __restrict__ b_r2,
    const float* __restrict__ W_r3, const float* __restrict__ b_r3,
    float* __restrict__ out)
{
    __shared__ float gl[64];
    __shared__ float row1[RU];
    __shared__ float row2[RU];
    __shared__ float fin[4];
    const int g = blockIdx.x;
    const int tid = threadIdx.x;
    const int slot = tid >> 6;
    const int lane = tid & 63;

    if (tid < 64) gl[tid] = gemb[g * D + tid];
    __syncthreads();

    float a1 = b_r1[tid];
#pragma unroll 8
    for (int k = 0; k < 64; ++k) a1 += gl[k] * W_r1[k * RU + tid];
    row1[tid] = selu_f(a1);
    __syncthreads();

    float a2 = b_r2[tid];
#pragma unroll 8
    for (int k = 0; k < RU; ++k) a2 += row1[k] * W_r2[k * RU + tid];
    row2[tid] = selu_f(a2);
    __syncthreads();

    float p = row2[tid] * W_r3[tid];
#pragma unroll
    for (int off = 32; off >= 1; off >>= 1)
        p += __shfl_down(p, off, 64);
    if (lane == 0) fin[slot] = p;
    __syncthreads();
    if (tid == 0)
        out[g] = fin[0] + fin[1] + fin[2] + fin[3] + b_r3[0];
}

extern "C" void kernel_launch(void* const* d_in, const int* in_sizes, int n_in,
                              void* d_out, int out_size, void* d_ws, size_t ws_size,
                              hipStream_t stream)
{
    const float* states_action = (const float*)d_in[0];
    const float* W_msg = (const float*)d_in[1];
    const float* b_msg = (const float*)d_in[2];
    const float* W_gcn = (const float*)d_in[3];
    const float* b_gcn = (const float*)d_in[4];
    const float* W_r1 = (const float*)d_in[5];
    const float* b_r1 = (const float*)d_in[6];
    const float* W_r2 = (const float*)d_in[7];
    const float* b_r2 = (const float*)d_in[8];
    const float* W_r3 = (const float*)d_in[9];
    const float* b_r3 = (const float*)d_in[10];
    const int* gid = (const int*)d_in[11];
    const int* first = (const int*)d_in[12];
    const int* second = (const int*)d_in[13];

    const int n_links = in_sizes[0] / D;     // 100000
    const int n_edges = in_sizes[12];        // 1600000
    const int G = out_size;                  // 256
    const int nbins = (n_links + 127) >> BIN_SHIFT;   // 782

    char* ws2 = (char*)d_ws;
    auto alloc = [&](size_t bytes) {
        char* p = ws2; ws2 += (bytes + 63) & ~(size_t)63; return p;
    };
    unsigned short* Sb = (unsigned short*)alloc((size_t)n_links * D * 2);       // 12.8 MB
    unsigned short* Pb = (unsigned short*)alloc((size_t)(n_links + 1) * D * 2); // 12.8 MB (+sentinel row)
    float* gemb = (float*)alloc((size_t)G * D * sizeof(float));
    int* row_ptr = (int*)alloc((size_t)(n_links + 1) * sizeof(int));
    int* grow = (int*)alloc((size_t)(G + 1) * sizeof(int));
    int* ghist = (int*)alloc((size_t)nbins * NSB * sizeof(int));
    unsigned* tmp = (unsigned*)alloc((size_t)n_edges * sizeof(unsigned));       // 6.4 MB (reused as tinfo)
    int* sfirst = (int*)alloc((size_t)(n_edges + 64) * sizeof(int));            // 6.4 MB
    unsigned short* WAh = (unsigned short*)alloc(4096 * 2);
    unsigned short* WAl = (unsigned short*)alloc(4096 * 2);
    unsigned short* WBh = (unsigned short*)alloc(4096 * 2);
    unsigned short* WBl = (unsigned short*)alloc(4096 * 2);
    unsigned short* WGh = (unsigned short*)alloc(4096 * 2);
    int* btot = (int*)alloc((size_t)nbins * sizeof(int));
    int* ptotv = (int*)alloc((size_t)nbins * sizeof(int));
    int* ptile = (int*)alloc((size_t)(n_links + 1) * sizeof(int));
    float* cstar = (float*)alloc(64 * sizeof(float));
    // tinfo aliases tmp: tmp is dead after binsortD_kernel; tbuild_kernel runs
    // strictly later on the same stream. Max tiles = E/16 + L = 200000 (+8 pad)
    // ints = 0.8 MB << 6.4 MB.
    int* tinfoA = (int*)tmp;

    // ---- input conversion + weight prep + atomic-free CSR build ----
    hipMemsetAsync(gemb, 0, (size_t)G * D * sizeof(float), stream);
    s2bf_kernel<<<1024, 256, 0, stream>>>(states_action, Sb, n_links * D / 4);
    wprep_kernel<<<16, 256, 0, stream>>>(W_msg, W_gcn, b_gcn, WAh, WAl, WBh, WBl,
                                         WGh, cstar, Pb, n_links);
    histA_kernel<<<NSB, 256, 0, stream>>>(second, ghist, n_edges, nbins);
    sumbins_kernel<<<nbins, 64, 0, stream>>>(ghist, btot, nbins);
    scanS_kernel<<<1, 1024, 0, stream>>>(btot, nbins);
    scatterC_kernel<<<NSB, 256, 0, stream>>>(first, second, ghist, btot, tmp,
                                             n_edges, nbins);
    binsortD_kernel<<<nbins, 256, 0, stream>>>(tmp, btot, sfirst, row_ptr, ptotv,
                                               n_edges, n_links, nbins);
    scanS_kernel<<<1, 1024, 0, stream>>>(ptotv, nbins);
    tbuild_kernel<<<nbins, 256, 0, stream>>>(row_ptr, ptotv, ptile, tinfoA,
                                             n_links, nbins);
    growfind_kernel<<<2, 256, 0, stream>>>(gid, grow, n_links, G);

    // ---- T = 4 message-passing iterations (state lives in Sb, bf16) ----
    const int edge_blocks = (n_links + 4 * CHUNK - 1) / (4 * CHUNK);  // 3125
    for (int t = 0; t < 4; ++t) {
        p_mfma_kernel<<<782, 256, 0, stream>>>(Sb, WAh, WAl, Pb, n_links);
        edge_link_kernel<<<edge_blocks, 256, 0, stream>>>(Sb, Pb, sfirst, tinfoA,
                                                          ptile, b_msg, WBh, WBl,
                                                          WGh, b_gcn, cstar,
                                                          n_links);
    }

    // ---- readout ----
    gsum8_kernel<<<G * 8, 256, 0, stream>>>(Sb, grow, gemb);
    mlp_kernel<<<G, 256, 0, stream>>>(gemb, W_r1, b_r1, W_r2, b_r2,
                                      W_r3, b_r3, (float*)d_out);
}

// Round 8
// 542.755 us; speedup vs baseline: 1.0123x; 1.0123x over previous
//
#include <hip/hip_runtime.h>
#include <hip/hip_bf16.h>
#include <math.h>

#define D 64
#define RU 256
#define CHUNK 16
#define QSTRIDE 68
#define BIN_SHIFT 7          // 128 links per coarse bin
#define NSB 128              // setup blocks for histA/scatterC

#if __has_builtin(__builtin_amdgcn_exp2f)
#define EXP2F(x) __builtin_amdgcn_exp2f(x)
#else
#define EXP2F(x) exp2f(x)
#endif

typedef short bf16x8 __attribute__((ext_vector_type(8)));
typedef float f32x4 __attribute__((ext_vector_type(4)));

__device__ __forceinline__ float selu_f(float x) {
    return x > 0.0f ? 1.0507009873554805f * x
                    : 1.7580993408473766f * (__expf(x) - 1.0f);
}

// input pre-scaled by log2(e): x2 = log2e * x. selu(x) =
// 1.7581*exp2(min(x2,0)) + (1.0507*ln2)*max(x2,0) - 1.7581
// note: x2 = -inf gives exactly -1.7580993408473766f (sentinel path)
__device__ __forceinline__ float selu_x2(float x2) {
    const float p = fmaxf(x2, 0.0f);
    const float n = fminf(x2, 0.0f);
    const float e = EXP2F(n);
    return fmaf(1.7580993408473766f, e, fmaf(0.72829042516f, p, -1.7580993408473766f));
}

__device__ __forceinline__ short f2bf_rtne(float x) {
    union { float f; unsigned u; } v; v.f = x;
    unsigned r = (v.u + 0x7FFFu + ((v.u >> 16) & 1u)) >> 16;
    return (short)r;
}
__device__ __forceinline__ float bf2f(short s) {
    union { float f; unsigned u; } v; v.u = ((unsigned)(unsigned short)s) << 16;
    return v.f;
}
__device__ __forceinline__ unsigned packpair(float a, float b) {
    float2 p; p.x = a; p.y = b;
    __hip_bfloat162 hb = __float22bfloat162_rn(p);
    return *(unsigned*)&hb;
}

__device__ __forceinline__ bf16x8 pack8(const float* v) {
    union { bf16x8 v; unsigned u[4]; } H;
#pragma unroll
    for (int j = 0; j < 4; ++j) H.u[j] = packpair(v[2 * j], v[2 * j + 1]);
    return H.v;
}

// fragment layout index: element i of the (ks,jt) B-fragment for lane (qd,m)
#define FIDX(ks, jt, qd, m) ((((((ks) * 4 + (jt)) * 4 + (qd)) * 16) + (m)) * 8)

// ================= one-shot weight fragment prep (fp32 -> bf16 hi/lo) =======
// Also: sentinel P row (bf16 -inf) + cstar[col] = relu(b + c0*colsum(Wgcn_bf16))
__global__ __launch_bounds__(256) void wprep_kernel(
    const float* __restrict__ W_msg, const float* __restrict__ W_gcn,
    const float* __restrict__ b_gcn,
    unsigned short* __restrict__ WAh, unsigned short* __restrict__ WAl,
    unsigned short* __restrict__ WBh, unsigned short* __restrict__ WBl,
    unsigned short* __restrict__ WGh, float* __restrict__ cstar,
    unsigned short* __restrict__ Pb, int n_links)
{
    const float LOG2E = 1.4426950408889634f;
    const int t = blockIdx.x * 256 + threadIdx.x;

    if (blockIdx.x == 0 && threadIdx.x < 64) {
        const int col = threadIdx.x;
        Pb[(size_t)n_links * 64 + col] = 0xFF80;   // bf16 -inf sentinel row
        const float c0 = bf2f(f2bf_rtne(-1.7580993408473766f));
        float acc = b_gcn[col];
        for (int k = 0; k < 64; ++k)
            acc = fmaf(c0, bf2f(f2bf_rtne(W_gcn[k * 64 + col])), acc);
        cstar[col] = fmaxf(acc, 0.0f);
    }

    if (t >= 4096) return;
    const int i  = t & 7;
    const int m  = (t >> 3) & 15;
    const int qd = (t >> 7) & 3;
    const int jt = (t >> 9) & 3;
    const int ks = t >> 11;
    const int kk = ks * 32 + qd * 8 + i;
    const int nn = jt * 16 + m;

    float w = W_msg[kk * 64 + nn] * LOG2E;
    short hi = f2bf_rtne(w);
    WAh[t] = (unsigned short)hi;
    WAl[t] = (unsigned short)f2bf_rtne(w - bf2f(hi));

    w = W_msg[(64 + kk) * 64 + nn] * LOG2E;
    hi = f2bf_rtne(w);
    WBh[t] = (unsigned short)hi;
    WBl[t] = (unsigned short)f2bf_rtne(w - bf2f(hi));

    WGh[t] = (unsigned short)f2bf_rtne(W_gcn[kk * 64 + nn]);
}

// ================= input conversion: fp32 state -> bf16 =================
__global__ __launch_bounds__(256) void s2bf_kernel(
    const float* __restrict__ in, unsigned short* __restrict__ out, int n4)
{
    for (int i = blockIdx.x * 256 + threadIdx.x; i < n4; i += gridDim.x * 256) {
        const float4 v = ((const float4*)in)[i];
        uint2 o;
        o.x = packpair(v.x, v.y);
        o.y = packpair(v.z, v.w);
        ((uint2*)out)[i] = o;
    }
}

// ================= atomic-free CSR build (hierarchical scans) ===============

__global__ __launch_bounds__(256) void histA_kernel(
    const int* __restrict__ second, int* __restrict__ ghist,
    int n_edges, int nbins)
{
    __shared__ int lhist[1024];
    for (int i = threadIdx.x; i < nbins; i += 256) lhist[i] = 0;
    __syncthreads();
    const int per = (n_edges + gridDim.x - 1) / gridDim.x;
    const int e0 = blockIdx.x * per;
    const int e1 = min(e0 + per, n_edges);
    for (int e = e0 + threadIdx.x; e < e1; e += 256)
        atomicAdd(&lhist[second[e] >> BIN_SHIFT], 1);
    __syncthreads();
    for (int i = threadIdx.x; i < nbins; i += 256)
        ghist[i * gridDim.x + blockIdx.x] = lhist[i];
}

// per-bin: exclusive scan of the NSB=128 per-block counters (in place) + bin total
__global__ __launch_bounds__(64) void sumbins_kernel(
    int* __restrict__ ghist, int* __restrict__ btot, int nbins)
{
    const int b = blockIdx.x, tid = threadIdx.x;
    const int d0 = ghist[b * NSB + tid];
    const int d1 = ghist[b * NSB + 64 + tid];
    int p0 = d0, p1 = d1;
#pragma unroll
    for (int off = 1; off < 64; off <<= 1) {
        const int t0 = __shfl_up(p0, off, 64);
        const int t1 = __shfl_up(p1, off, 64);
        if (tid >= off) { p0 += t0; p1 += t1; }
    }
    const int tot0 = __shfl(p0, 63, 64);
    ghist[b * NSB + tid] = p0 - d0;
    ghist[b * NSB + 64 + tid] = tot0 + p1 - d1;
    if (tid == 63) btot[b] = tot0 + p1;
}

// single-block exclusive scan, n <= 1024, in place
__global__ __launch_bounds__(1024) void scanS_kernel(int* __restrict__ data, int n)
{
    __shared__ int wsum[16], woff[16];
    const int tid = threadIdx.x, wave = tid >> 6, lane = tid & 63;
    const int x = (tid < n) ? data[tid] : 0;
    int v = x;
#pragma unroll
    for (int off = 1; off < 64; off <<= 1) {
        const int t = __shfl_up(v, off, 64);
        if (lane >= off) v += t;
    }
    if (lane == 63) wsum[wave] = v;
    __syncthreads();
    if (wave == 0) {
        int s = (lane < 16) ? wsum[lane] : 0;
#pragma unroll
        for (int off = 1; off < 16; off <<= 1) {
            const int t = __shfl_up(s, off, 64);
            if (lane >= off) s += t;
        }
        if (lane < 16) woff[lane] = s - wsum[lane];
    }
    __syncthreads();
    if (tid < n) data[tid] = woff[wave] + v - x;
}

// packed tmp: bits [0,20) = first, bits [20,27) = second & 127
__global__ __launch_bounds__(256) void scatterC_kernel(
    const int* __restrict__ first, const int* __restrict__ second,
    const int* __restrict__ ghist, const int* __restrict__ btot,
    unsigned* __restrict__ tmp, int n_edges, int nbins)
{
    __shared__ int lcur[1024];
    for (int i = threadIdx.x; i < nbins; i += 256)
        lcur[i] = ghist[i * NSB + blockIdx.x] + btot[i];
    __syncthreads();
    const int per = (n_edges + gridDim.x - 1) / gridDim.x;
    const int e0 = blockIdx.x * per;
    const int e1 = min(e0 + per, n_edges);
    for (int e = e0 + threadIdx.x; e < e1; e += 256) {
        const int s = second[e];
        const int pos = atomicAdd(&lcur[s >> BIN_SHIFT], 1);
        tmp[pos] = (unsigned)first[e] | ((unsigned)(s & 127) << 20);
    }
}

__global__ __launch_bounds__(256) void binsortD_kernel(
    const unsigned* __restrict__ tmp, const int* __restrict__ btot,
    int* __restrict__ sfirst, int* __restrict__ row_ptr, int* __restrict__ ptot,
    int n_edges, int n_links, int nbins)
{
    __shared__ int ldeg[128];
    __shared__ int lpre[128];
    __shared__ int lcur[128];
    const int b = blockIdx.x;
    const int tid = threadIdx.x;
    const int lbase = b << BIN_SHIFT;
    const int nl = min(128, n_links - lbase);
    const int eb = btot[b];
    const int ee = (b + 1 < nbins) ? btot[b + 1] : n_edges;

    if (tid < 128) ldeg[tid] = 0;
    __syncthreads();
    for (int e = eb + tid; e < ee; e += 256)
        atomicAdd(&ldeg[tmp[e] >> 20], 1);
    __syncthreads();
    if (tid < 64) {
        const int d0 = ldeg[tid], d1 = ldeg[64 + tid];
        int p0 = d0, p1 = d1;
#pragma unroll
        for (int off = 1; off < 64; off <<= 1) {
            const int t0 = __shfl_up(p0, off, 64);
            const int t1 = __shfl_up(p1, off, 64);
            if (tid >= off) { p0 += t0; p1 += t1; }
        }
        const int tot0 = __shfl(p0, 63, 64);
        lpre[tid] = p0 - d0;
        lpre[64 + tid] = tot0 + p1 - d1;
        // padded tile-count total for this bin
        const int n0 = (d0 + 15) >> 4, n1 = (d1 + 15) >> 4;
        int q0 = n0, q1 = n1;
#pragma unroll
        for (int off = 1; off < 64; off <<= 1) {
            const int t0 = __shfl_up(q0, off, 64);
            const int t1 = __shfl_up(q1, off, 64);
            if (tid >= off) { q0 += t0; q1 += t1; }
        }
        if (tid == 63) ptot[b] = q0 + q1;
    }
    __syncthreads();
    if (tid < nl) row_ptr[lbase + tid] = eb + lpre[tid];
    if (b == nbins - 1 && tid == 0) row_ptr[n_links] = n_edges;
    if (tid < 128) lcur[tid] = lpre[tid];
    __syncthreads();
    for (int e = eb + tid; e < ee; e += 256) {
        const unsigned v = tmp[e];
        const int pos = eb + atomicAdd(&lcur[v >> 20], 1);
        sfirst[pos] = (int)(v & 0xFFFFFu);
    }
    if (b == 0)
        for (int i = tid; i < 64; i += 256) sfirst[n_edges + i] = 0;  // pipeline pad
}

// build per-tile descriptors: tinfo[t] = eo | li<<21 (4b) | last<<25 | vcnt<<26
// and per-link tile prefix ptile[l] (ptile[n_links] = total tiles)
// NOTE: tinfo aliases the (dead-after-binsortD) tmp buffer.
__global__ __launch_bounds__(256) void tbuild_kernel(
    const int* __restrict__ row_ptr, const int* __restrict__ tbase,
    int* __restrict__ ptile, int* __restrict__ tinfo,
    int n_links, int nbins)
{
    __shared__ int rpl[130];
    __shared__ int ltp[130];
    const int b = blockIdx.x, tid = threadIdx.x;
    const int lbase = b << BIN_SHIFT;
    const int nl = min(128, n_links - lbase);
    if (tid <= nl) rpl[tid] = row_ptr[lbase + tid];
    __syncthreads();
    if (tid < 64) {
        const int d0 = (tid < nl) ? rpl[tid + 1] - rpl[tid] : 0;
        const int d1 = (64 + tid < nl) ? rpl[64 + tid + 1] - rpl[64 + tid] : 0;
        const int n0 = (d0 + 15) >> 4, n1 = (d1 + 15) >> 4;
        int p0 = n0, p1 = n1;
#pragma unroll
        for (int off = 1; off < 64; off <<= 1) {
            const int t0 = __shfl_up(p0, off, 64);
            const int t1 = __shfl_up(p1, off, 64);
            if (tid >= off) { p0 += t0; p1 += t1; }
        }
        const int tot0 = __shfl(p0, 63, 64);
        ltp[tid] = p0 - n0;
        ltp[64 + tid] = tot0 + p1 - n1;
        if (tid == 63) ltp[128] = tot0 + p1;
    }
    __syncthreads();
    const int tb = tbase[b];
    if (tid <= nl) ptile[lbase + tid] = tb + ltp[tid];
    const int ntb = ltp[128];
    for (int tl = tid; tl < ntb; tl += 256) {
        int lo = 0, hi = nl - 1;
        while (lo < hi) {                      // largest li with ltp[li] <= tl
            const int mid = (lo + hi + 1) >> 1;
            if (ltp[mid] <= tl) lo = mid; else hi = mid - 1;
        }
        const int li = lo;
        const int eo = rpl[li] + ((tl - ltp[li]) << 4);
        const int rend = rpl[li + 1];
        const int vc = min(16, rend - eo);
        const int last = (eo + 16 >= rend) ? 1 : 0;
        tinfo[tb + tl] = eo | ((li & 15) << 21) | (last << 25) | (vc << 26);
    }
    if (b == nbins - 1 && tid < 8) tinfo[tb + ntb + tid] = 0;  // SENT pads (vcnt=0)
}

__global__ __launch_bounds__(256) void growfind_kernel(
    const int* __restrict__ gid, int* __restrict__ grow, int n_links, int G)
{
    const int g = blockIdx.x * blockDim.x + threadIdx.x;
    if (g > G) return;
    if (g == G) { grow[G] = n_links; return; }
    int lo = 0, hi = n_links;
    while (lo < hi) {
        const int mid = (lo + hi) >> 1;
        if (gid[mid] < g) lo = mid + 1; else hi = mid;
    }
    grow[g] = lo;
}

// ---------------- P via MFMA: bf16 state A (direct loads), split-B ----------
__global__ __launch_bounds__(256) void p_mfma_kernel(
    const unsigned short* __restrict__ Sb,
    const unsigned short* __restrict__ WAh, const unsigned short* __restrict__ WAl,
    unsigned short* __restrict__ P, int n_links)
{
    const int tid = threadIdx.x;
    const int wave = tid >> 6;
    const int lane = tid & 63;
    const int m = lane & 15;
    const int qd = lane >> 4;

    bf16x8 Bh[2][4], Bl[2][4];
#pragma unroll
    for (int ks = 0; ks < 2; ++ks)
#pragma unroll
        for (int jt = 0; jt < 4; ++jt) {
            const int off = FIDX(ks, jt, qd, m);
            Bh[ks][jt] = *(const bf16x8*)(WAh + off);
            Bl[ks][jt] = *(const bf16x8*)(WAl + off);
        }
    const bf16x8 z = (bf16x8){0, 0, 0, 0, 0, 0, 0, 0};

    const int ngroups = (n_links + 63) >> 6;
    for (int g = blockIdx.x; g < ngroups; g += gridDim.x) {
        const int base = g * 64 + wave * 16;
        const int l = base + m;
        bf16x8 Ah0 = z, Ah1 = z;
        if (l < n_links) {
            Ah0 = *(const bf16x8*)(Sb + (size_t)l * D + qd * 8);
            Ah1 = *(const bf16x8*)(Sb + (size_t)l * D + 32 + qd * 8);
        }
        f32x4 accP[4];
#pragma unroll
        for (int jt = 0; jt < 4; ++jt) {
            accP[jt] = (f32x4){0.f, 0.f, 0.f, 0.f};
            accP[jt] = __builtin_amdgcn_mfma_f32_16x16x32_bf16(Ah0, Bh[0][jt], accP[jt], 0, 0, 0);
            accP[jt] = __builtin_amdgcn_mfma_f32_16x16x32_bf16(Ah0, Bl[0][jt], accP[jt], 0, 0, 0);
            accP[jt] = __builtin_amdgcn_mfma_f32_16x16x32_bf16(Ah1, Bh[1][jt], accP[jt], 0, 0, 0);
            accP[jt] = __builtin_amdgcn_mfma_f32_16x16x32_bf16(Ah1, Bl[1][jt], accP[jt], 0, 0, 0);
        }
#pragma unroll
        for (int r = 0; r < 4; ++r) {
            const int lr = base + qd * 4 + r;
            if (lr < n_links) {
#pragma unroll
                for (int jt = 0; jt < 4; ++jt)
                    P[(size_t)lr * D + jt * 16 + m] =
                        (unsigned short)f2bf_rtne(accP[jt][r]);
            }
        }
    }
}

// ---------------- link-centric fused edge kernel (tinfo-driven) -------------
// Round 7: revert round-6 packed-f32 regression to the round-5 scalar body;
// CHUNK 8 -> 16 so phase-1's 16-row MFMA is fully utilized (was half zeros)
// and per-wave prologue amortizes over 2x links. tinfo layout: li 4 bits.
__global__ __launch_bounds__(256, 4) void edge_link_kernel(
    unsigned short* __restrict__ Sb, const unsigned short* __restrict__ P,
    const int* __restrict__ sfirst, const int* __restrict__ tinfo,
    const int* __restrict__ ptile,
    const float* __restrict__ b_msg,
    const unsigned short* __restrict__ WBh, const unsigned short* __restrict__ WBl,
    const unsigned short* __restrict__ WGh,
    const float* __restrict__ b_gcn, const float* __restrict__ cstar,
    int n_links)
{
    __shared__ float qt[4][CHUNK * QSTRIDE + 4];
    __shared__ float cbl[64];
    const int tid = threadIdx.x;
    const int wave = tid >> 6;
    const int lane = tid & 63;
    const int m = lane & 15;
    const int qd = lane >> 4;

    // each wave writes the full cbl (benign identical-value race across waves)
    cbl[lane] = cstar[lane];

    const int l0 = (blockIdx.x * 4 + wave) * CHUNK;
    if (l0 >= n_links) return;
    const int nl = min(CHUNK, n_links - l0);

    const float LOG2E = 1.4426950408889634f;
    float bmsgC[4];
#pragma unroll
    for (int jt = 0; jt < 4; ++jt) bmsgC[jt] = b_msg[jt * 16 + m] * LOG2E;

    // ---- Phase 1: Q-tile from bf16 state chunk (A direct, pre-split B) ----
    // CHUNK=16: all 16 MFMA rows carry a live link.
    {
        const bf16x8 z = (bf16x8){0, 0, 0, 0, 0, 0, 0, 0};
        const int l = l0 + m;
        bf16x8 Ah0 = z, Ah1 = z;
        if (l < n_links) {
            Ah0 = *(const bf16x8*)(Sb + (size_t)l * D + qd * 8);
            Ah1 = *(const bf16x8*)(Sb + (size_t)l * D + 32 + qd * 8);
        }
        f32x4 accQ[4];
#pragma unroll
        for (int jt = 0; jt < 4; ++jt) accQ[jt] = (f32x4){0.f, 0.f, 0.f, 0.f};
#pragma unroll
        for (int ks = 0; ks < 2; ++ks) {
            bf16x8 WbH[4], WbL[4];
#pragma unroll
            for (int jt = 0; jt < 4; ++jt) {
                const int off = FIDX(ks, jt, qd, m);
                WbH[jt] = *(const bf16x8*)(WBh + off);
                WbL[jt] = *(const bf16x8*)(WBl + off);
            }
            const bf16x8 A = ks ? Ah1 : Ah0;
#pragma unroll
            for (int jt = 0; jt < 4; ++jt) {
                accQ[jt] = __builtin_amdgcn_mfma_f32_16x16x32_bf16(A, WbH[jt], accQ[jt], 0, 0, 0);
                accQ[jt] = __builtin_amdgcn_mfma_f32_16x16x32_bf16(A, WbL[jt], accQ[jt], 0, 0, 0);
            }
        }
#pragma unroll
        for (int r = 0; r < 4; ++r) {
            const int row = qd * 4 + r;
#pragma unroll
            for (int jt = 0; jt < 4; ++jt)
                qt[wave][row * QSTRIDE + jt * 16 + m] = accQ[jt][r] + bmsgC[jt];
        }
    }

    // ---- W_gcn B-frags + scalar bias ----
    bf16x8 Gh[2][4];
#pragma unroll
    for (int ks = 0; ks < 2; ++ks)
#pragma unroll
        for (int jt = 0; jt < 4; ++jt)
            Gh[ks][jt] = *(const bf16x8*)(WGh + FIDX(ks, jt, qd, m));

    float bias_gcn[4];
#pragma unroll
    for (int jt = 0; jt < 4; ++jt) bias_gcn[jt] = b_gcn[jt * 16 + m];

    // ---- tile range for this chunk + zero empty links ----
    const int tpv = ptile[l0 + min(lane, nl)];
#pragma unroll
    for (int i = 0; i < CHUNK; ++i) {
        if (i < nl && __shfl(tpv, i + 1, 64) == __shfl(tpv, i, 64))
            Sb[(size_t)(l0 + i) * D + lane] = 0;
    }
    const int tbeg = __builtin_amdgcn_readfirstlane(tpv);
    const int tend = __builtin_amdgcn_readfirstlane(__shfl(tpv, nl, 64));
    if (tbeg >= tend) return;

    // ---- pipeline prologue: tinfo 3 deep, sf 1 deep, p current ----
    int ti0 = tinfo[tbeg];
    int ti1 = tinfo[tbeg + 1];
    int ti2 = tinfo[tbeg + 2];

    bf16x8 p00, p01;
    {
        const int eo = ti0 & 0x1FFFFF, vc = (ti0 >> 26) & 31;
        int sf = sfirst[eo + m];
        sf = (m < vc) ? sf : n_links;
        const unsigned short* Pr = P + (size_t)sf * D;
        p00 = *(const bf16x8*)(Pr + qd * 8);
        p01 = *(const bf16x8*)(Pr + 32 + qd * 8);
    }
    int sf1;
    {
        const int eo = ti1 & 0x1FFFFF, vc = (ti1 >> 26) & 31;
        int sf = sfirst[eo + m];
        sf1 = (m < vc) ? sf : n_links;
    }

    float rsum[4] = {0.f, 0.f, 0.f, 0.f};

    for (int t = tbeg; t < tend; ++t) {
        const int tiN = tinfo[t + 3];                 // padded past global end
        // sf for t+2
        const int eo2 = ti2 & 0x1FFFFF, vc2 = (ti2 >> 26) & 31;
        int sf2 = sfirst[eo2 + m];
        sf2 = (m < vc2) ? sf2 : n_links;
        // p for t+1
        const unsigned short* Pr1 = P + (size_t)sf1 * D;
        const bf16x8 p10 = *(const bf16x8*)(Pr1 + qd * 8);
        const bf16x8 p11 = *(const bf16x8*)(Pr1 + 32 + qd * 8);

        const int li0 = (ti0 >> 21) & 15;
        const int vc0 = (ti0 >> 26) & 31;
        const int qoff = li0 * QSTRIDE + qd * 8;

        // half A: qt re-read (2 x float4), selu, pack
        float msgA[8];
        {
            const float4 qa0 = *(const float4*)&qt[wave][qoff];
            const float4 qa1 = *(const float4*)&qt[wave][qoff + 4];
#pragma unroll
            for (int i = 0; i < 4; ++i) {
                msgA[i]     = selu_x2(bf2f(p00[i])     + qa0[i]);
                msgA[4 + i] = selu_x2(bf2f(p00[4 + i]) + qa1[i]);
            }
        }
        const bf16x8 Ah0 = pack8(msgA);
        // half B
        float msgB[8];
        {
            const float4 qb0 = *(const float4*)&qt[wave][qoff + 32];
            const float4 qb1 = *(const float4*)&qt[wave][qoff + 36];
#pragma unroll
            for (int i = 0; i < 4; ++i) {
                msgB[i]     = selu_x2(bf2f(p01[i])     + qb0[i]);
                msgB[4 + i] = selu_x2(bf2f(p01[4 + i]) + qb1[i]);
            }
        }
        const bf16x8 Ah1 = pack8(msgB);

        f32x4 acc[4];
#pragma unroll
        for (int jt = 0; jt < 4; ++jt) {
            const float b = bias_gcn[jt];
            acc[jt] = (f32x4){b, b, b, b};
            acc[jt] = __builtin_amdgcn_mfma_f32_16x16x32_bf16(Ah0, Gh[0][jt], acc[jt], 0, 0, 0);
            acc[jt] = __builtin_amdgcn_mfma_f32_16x16x32_bf16(Ah1, Gh[1][jt], acc[jt], 0, 0, 0);
        }
#pragma unroll
        for (int jt = 0; jt < 4; ++jt)
#pragma unroll
            for (int r = 0; r < 4; ++r)
                rsum[jt] += fmaxf(acc[jt][r], 0.0f);

        if (ti0 & (1 << 25)) {                        // last tile of link li0
            const int over = qd * 4 + 4 - vc0;        // invalid rows in this qd group
            const float cnt = (float)max(0, min(4, over));
#pragma unroll
            for (int jt = 0; jt < 4; ++jt) {
                rsum[jt] -= cbl[jt * 16 + m] * cnt;
                rsum[jt] += __shfl_xor(rsum[jt], 16, 64);
                rsum[jt] += __shfl_xor(rsum[jt], 32, 64);
            }
            const float outv = (qd == 0) ? rsum[0] : (qd == 1) ? rsum[1]
                             : (qd == 2) ? rsum[2] : rsum[3];
            Sb[(size_t)(l0 + li0) * D + lane] = (unsigned short)f2bf_rtne(outv);
#pragma unroll
            for (int jt = 0; jt < 4; ++jt) rsum[jt] = 0.0f;
        }

        ti0 = ti1; ti1 = ti2; ti2 = tiN;
        sf1 = sf2;
        p00 = p10; p01 = p11;
    }
}

// ---------------- readout: parallel segment-sum (bf16 S) + tiny MLP ---------
__global__ __launch_bounds__(256) void gsum8_kernel(
    const unsigned short* __restrict__ Sb, const int* __restrict__ grow,
    float* __restrict__ gemb)
{
    __shared__ float red[4][64];
    const int g = blockIdx.x >> 3;
    const int slice = blockIdx.x & 7;
    const int slot = threadIdx.x >> 6;
    const int j = threadIdx.x & 63;
    const int ls = grow[g], le = grow[g + 1];
    float acc = 0.0f;
    for (int l = ls + slice * 4 + slot; l < le; l += 32)
        acc += bf2f((short)Sb[(size_t)l * D + j]);
    red[slot][j] = acc;
    __syncthreads();
    if (slot == 0)
        atomicAdd(&gemb[g * D + j], red[0][j] + red[1][j] + red[2][j] + red[3][j]);
}

__global__ __launch_bounds__(256) void mlp_kernel(
    const float* __restrict__ gemb,
    const float* __restrict__ W_r1, const float* __restrict__ b_r1,
    const float* __restrict__ W_r2, const float* __restrict__ b_r2,
    const float* __restrict__ W_r3, const float* __restrict__ b_r3,
    float* __restrict__ out)
{
    __shared__ float gl[64];
    __shared__ float row1[RU];
    __shared__ float row2[RU];
    __shared__ float fin[4];
    const int g = blockIdx.x;
    const int tid = threadIdx.x;
    const int slot = tid >> 6;
    const int lane = tid & 63;

    if (tid < 64) gl[tid] = gemb[g * D + tid];
    __syncthreads();

    float a1 = b_r1[tid];
#pragma unroll 8
    for (int k = 0; k < 64; ++k) a1 += gl[k] * W_r1[k * RU + tid];
    row1[tid] = selu_f(a1);
    __syncthreads();

    float a2 = b_r2[tid];
#pragma unroll 8
    for (int k = 0; k < RU; ++k) a2 += row1[k] * W_r2[k * RU + tid];
    row2[tid] = selu_f(a2);
    __syncthreads();

    float p = row2[tid] * W_r3[tid];
#pragma unroll
    for (int off = 32; off >= 1; off >>= 1)
        p += __shfl_down(p, off, 64);
    if (lane == 0) fin[slot] = p;
    __syncthreads();
    if (tid == 0)
        out[g] = fin[0] + fin[1] + fin[2] + fin[3] + b_r3[0];
}

extern "C" void kernel_launch(void* const* d_in, const int* in_sizes, int n_in,
                              void* d_out, int out_size, void* d_ws, size_t ws_size,
                              hipStream_t stream)
{
    const float* states_action = (const float*)d_in[0];
    const float* W_msg = (const float*)d_in[1];
    const float* b_msg = (const float*)d_in[2];
    const float* W_gcn = (const float*)d_in[3];
    const float* b_gcn = (const float*)d_in[4];
    const float* W_r1 = (const float*)d_in[5];
    const float* b_r1 = (const float*)d_in[6];
    const float* W_r2 = (const float*)d_in[7];
    const float* b_r2 = (const float*)d_in[8];
    const float* W_r3 = (const float*)d_in[9];
    const float* b_r3 = (const float*)d_in[10];
    const int* gid = (const int*)d_in[11];
    const int* first = (const int*)d_in[12];
    const int* second = (const int*)d_in[13];

    const int n_links = in_sizes[0] / D;     // 100000
    const int n_edges = in_sizes[12];        // 1600000
    const int G = out_size;                  // 256
    const int nbins = (n_links + 127) >> BIN_SHIFT;   // 782

    char* ws2 = (char*)d_ws;
    auto alloc = [&](size_t bytes) {
        char* p = ws2; ws2 += (bytes + 63) & ~(size_t)63; return p;
    };
    unsigned short* Sb = (unsigned short*)alloc((size_t)n_links * D * 2);       // 12.8 MB
    unsigned short* Pb = (unsigned short*)alloc((size_t)(n_links + 1) * D * 2); // 12.8 MB (+sentinel row)
    float* gemb = (float*)alloc((size_t)G * D * sizeof(float));
    int* row_ptr = (int*)alloc((size_t)(n_links + 1) * sizeof(int));
    int* grow = (int*)alloc((size_t)(G + 1) * sizeof(int));
    int* ghist = (int*)alloc((size_t)nbins * NSB * sizeof(int));
    unsigned* tmp = (unsigned*)alloc((size_t)n_edges * sizeof(unsigned));       // 6.4 MB (reused as tinfo)
    int* sfirst = (int*)alloc((size_t)(n_edges + 64) * sizeof(int));            // 6.4 MB
    unsigned short* WAh = (unsigned short*)alloc(4096 * 2);
    unsigned short* WAl = (unsigned short*)alloc(4096 * 2);
    unsigned short* WBh = (unsigned short*)alloc(4096 * 2);
    unsigned short* WBl = (unsigned short*)alloc(4096 * 2);
    unsigned short* WGh = (unsigned short*)alloc(4096 * 2);
    int* btot = (int*)alloc((size_t)nbins * sizeof(int));
    int* ptotv = (int*)alloc((size_t)nbins * sizeof(int));
    int* ptile = (int*)alloc((size_t)(n_links + 1) * sizeof(int));
    float* cstar = (float*)alloc(64 * sizeof(float));
    // tinfo aliases tmp: tmp is dead after binsortD_kernel; tbuild_kernel runs
    // strictly later on the same stream. Max tiles = E/16 + L = 200000 (+8 pad)
    // ints = 0.8 MB << 6.4 MB.
    int* tinfoA = (int*)tmp;

    // ---- input conversion + weight prep + atomic-free CSR build ----
    hipMemsetAsync(gemb, 0, (size_t)G * D * sizeof(float), stream);
    s2bf_kernel<<<1024, 256, 0, stream>>>(states_action, Sb, n_links * D / 4);
    wprep_kernel<<<16, 256, 0, stream>>>(W_msg, W_gcn, b_gcn, WAh, WAl, WBh, WBl,
                                         WGh, cstar, Pb, n_links);
    histA_kernel<<<NSB, 256, 0, stream>>>(second, ghist, n_edges, nbins);
    sumbins_kernel<<<nbins, 64, 0, stream>>>(ghist, btot, nbins);
    scanS_kernel<<<1, 1024, 0, stream>>>(btot, nbins);
    scatterC_kernel<<<NSB, 256, 0, stream>>>(first, second, ghist, btot, tmp,
                                             n_edges, nbins);
    binsortD_kernel<<<nbins, 256, 0, stream>>>(tmp, btot, sfirst, row_ptr, ptotv,
                                               n_edges, n_links, nbins);
    scanS_kernel<<<1, 1024, 0, stream>>>(ptotv, nbins);
    tbuild_kernel<<<nbins, 256, 0, stream>>>(row_ptr, ptotv, ptile, tinfoA,
                                             n_links, nbins);
    growfind_kernel<<<2, 256, 0, stream>>>(gid, grow, n_links, G);

    // ---- T = 4 message-passing iterations (state lives in Sb, bf16) ----
    const int edge_blocks = (n_links + 4 * CHUNK - 1) / (4 * CHUNK);  // 1563
    for (int t = 0; t < 4; ++t) {
        p_mfma_kernel<<<782, 256, 0, stream>>>(Sb, WAh, WAl, Pb, n_links);
        edge_link_kernel<<<edge_blocks, 256, 0, stream>>>(Sb, Pb, sfirst, tinfoA,
                                                          ptile, b_msg, WBh, WBl,
                                                          WGh, b_gcn, cstar,
                                                          n_links);
    }

    // ---- readout ----
    gsum8_kernel<<<G * 8, 256, 0, stream>>>(Sb, grow, gemb);
    mlp_kernel<<<G, 256, 0, stream>>>(gemb, W_r1, b_r1, W_r2, b_r2,
                                      W_r3, b_r3, (float*)d_out);
}

// Round 9
// 521.769 us; speedup vs baseline: 1.0530x; 1.0402x over previous
//
#include <hip/hip_runtime.h>
#include <hip/hip_bf16.h>
#include <math.h>

#define D 64
#define RU 256
#define CHUNK 8
#define QSTRIDE 68
#define BIN_SHIFT 7          // 128 links per coarse bin
#define NSB 256              // setup blocks for histA/scatterC (256 fills all CUs)

#if __has_builtin(__builtin_amdgcn_exp2f)
#define EXP2F(x) __builtin_amdgcn_exp2f(x)
#else
#define EXP2F(x) exp2f(x)
#endif

typedef short bf16x8 __attribute__((ext_vector_type(8)));
typedef float f32x4 __attribute__((ext_vector_type(4)));

__device__ __forceinline__ float selu_f(float x) {
    return x > 0.0f ? 1.0507009873554805f * x
                    : 1.7580993408473766f * (__expf(x) - 1.0f);
}

// input pre-scaled by log2(e): x2 = log2e * x. selu(x) =
// 1.7581*exp2(min(x2,0)) + (1.0507*ln2)*max(x2,0) - 1.7581
// note: x2 = -inf gives exactly -1.7580993408473766f (sentinel path)
__device__ __forceinline__ float selu_x2(float x2) {
    const float p = fmaxf(x2, 0.0f);
    const float n = fminf(x2, 0.0f);
    const float e = EXP2F(n);
    return fmaf(1.7580993408473766f, e, fmaf(0.72829042516f, p, -1.7580993408473766f));
}

__device__ __forceinline__ short f2bf_rtne(float x) {
    union { float f; unsigned u; } v; v.f = x;
    unsigned r = (v.u + 0x7FFFu + ((v.u >> 16) & 1u)) >> 16;
    return (short)r;
}
__device__ __forceinline__ float bf2f(short s) {
    union { float f; unsigned u; } v; v.u = ((unsigned)(unsigned short)s) << 16;
    return v.f;
}
__device__ __forceinline__ unsigned packpair(float a, float b) {
    float2 p; p.x = a; p.y = b;
    __hip_bfloat162 hb = __float22bfloat162_rn(p);
    return *(unsigned*)&hb;
}

__device__ __forceinline__ bf16x8 pack8(const float* v) {
    union { bf16x8 v; unsigned u[4]; } H;
#pragma unroll
    for (int j = 0; j < 4; ++j) H.u[j] = packpair(v[2 * j], v[2 * j + 1]);
    return H.v;
}

// fragment layout index: element i of the (ks,jt) B-fragment for lane (qd,m)
#define FIDX(ks, jt, qd, m) ((((((ks) * 4 + (jt)) * 4 + (qd)) * 16) + (m)) * 8)

// ================= one-shot weight fragment prep (fp32 -> bf16 hi/lo) =======
// Also: sentinel P row (bf16 -inf) + cstar[col] = relu(b + c0*colsum(Wgcn_bf16))
__global__ __launch_bounds__(256) void wprep_kernel(
    const float* __restrict__ W_msg, const float* __restrict__ W_gcn,
    const float* __restrict__ b_gcn,
    unsigned short* __restrict__ WAh, unsigned short* __restrict__ WAl,
    unsigned short* __restrict__ WBh, unsigned short* __restrict__ WBl,
    unsigned short* __restrict__ WGh, float* __restrict__ cstar,
    unsigned short* __restrict__ Pb, int n_links)
{
    const float LOG2E = 1.4426950408889634f;
    const int t = blockIdx.x * 256 + threadIdx.x;

    if (blockIdx.x == 0 && threadIdx.x < 64) {
        const int col = threadIdx.x;
        Pb[(size_t)n_links * 64 + col] = 0xFF80;   // bf16 -inf sentinel row
        const float c0 = bf2f(f2bf_rtne(-1.7580993408473766f));
        float acc = b_gcn[col];
        for (int k = 0; k < 64; ++k)
            acc = fmaf(c0, bf2f(f2bf_rtne(W_gcn[k * 64 + col])), acc);
        cstar[col] = fmaxf(acc, 0.0f);
    }

    if (t >= 4096) return;
    const int i  = t & 7;
    const int m  = (t >> 3) & 15;
    const int qd = (t >> 7) & 3;
    const int jt = (t >> 9) & 3;
    const int ks = t >> 11;
    const int kk = ks * 32 + qd * 8 + i;
    const int nn = jt * 16 + m;

    float w = W_msg[kk * 64 + nn] * LOG2E;
    short hi = f2bf_rtne(w);
    WAh[t] = (unsigned short)hi;
    WAl[t] = (unsigned short)f2bf_rtne(w - bf2f(hi));

    w = W_msg[(64 + kk) * 64 + nn] * LOG2E;
    hi = f2bf_rtne(w);
    WBh[t] = (unsigned short)hi;
    WBl[t] = (unsigned short)f2bf_rtne(w - bf2f(hi));

    WGh[t] = (unsigned short)f2bf_rtne(W_gcn[kk * 64 + nn]);
}

// ================= input conversion: fp32 state -> bf16 =================
__global__ __launch_bounds__(256) void s2bf_kernel(
    const float* __restrict__ in, unsigned short* __restrict__ out, int n4)
{
    for (int i = blockIdx.x * 256 + threadIdx.x; i < n4; i += gridDim.x * 256) {
        const float4 v = ((const float4*)in)[i];
        uint2 o;
        o.x = packpair(v.x, v.y);
        o.y = packpair(v.z, v.w);
        ((uint2*)out)[i] = o;
    }
}

// ================= atomic-free CSR build (hierarchical scans) ===============

__global__ __launch_bounds__(256) void histA_kernel(
    const int* __restrict__ second, int* __restrict__ ghist,
    int n_edges, int nbins)
{
    __shared__ int lhist[1024];
    for (int i = threadIdx.x; i < nbins; i += 256) lhist[i] = 0;
    __syncthreads();
    const int per = (n_edges + gridDim.x - 1) / gridDim.x;
    const int e0 = blockIdx.x * per;
    const int e1 = min(e0 + per, n_edges);
    for (int e = e0 + threadIdx.x; e < e1; e += 256)
        atomicAdd(&lhist[second[e] >> BIN_SHIFT], 1);
    __syncthreads();
    for (int i = threadIdx.x; i < nbins; i += 256)
        ghist[i * gridDim.x + blockIdx.x] = lhist[i];
}

// per-bin: exclusive scan of the NSB=256 per-block counters (in place) + bin total
// 64 threads handle 4 elements each (4 segment scans stitched serially).
__global__ __launch_bounds__(64) void sumbins_kernel(
    int* __restrict__ ghist, int* __restrict__ btot, int nbins)
{
    const int b = blockIdx.x, tid = threadIdx.x;
    int d[4], p[4];
#pragma unroll
    for (int k = 0; k < 4; ++k) {
        d[k] = ghist[b * NSB + k * 64 + tid];
        p[k] = d[k];
    }
#pragma unroll
    for (int off = 1; off < 64; off <<= 1) {
#pragma unroll
        for (int k = 0; k < 4; ++k) {
            const int t = __shfl_up(p[k], off, 64);
            if (tid >= off) p[k] += t;
        }
    }
    int base = 0;
#pragma unroll
    for (int k = 0; k < 4; ++k) {
        const int tot = __shfl(p[k], 63, 64);
        ghist[b * NSB + k * 64 + tid] = base + p[k] - d[k];
        base += tot;
    }
    if (tid == 63) btot[b] = base;
}

// single-block exclusive scan, n <= 1024, in place
__global__ __launch_bounds__(1024) void scanS_kernel(int* __restrict__ data, int n)
{
    __shared__ int wsum[16], woff[16];
    const int tid = threadIdx.x, wave = tid >> 6, lane = tid & 63;
    const int x = (tid < n) ? data[tid] : 0;
    int v = x;
#pragma unroll
    for (int off = 1; off < 64; off <<= 1) {
        const int t = __shfl_up(v, off, 64);
        if (lane >= off) v += t;
    }
    if (lane == 63) wsum[wave] = v;
    __syncthreads();
    if (wave == 0) {
        int s = (lane < 16) ? wsum[lane] : 0;
#pragma unroll
        for (int off = 1; off < 16; off <<= 1) {
            const int t = __shfl_up(s, off, 64);
            if (lane >= off) s += t;
        }
        if (lane < 16) woff[lane] = s - wsum[lane];
    }
    __syncthreads();
    if (tid < n) data[tid] = woff[wave] + v - x;
}

// packed tmp: bits [0,20) = first, bits [20,27) = second & 127
__global__ __launch_bounds__(256) void scatterC_kernel(
    const int* __restrict__ first, const int* __restrict__ second,
    const int* __restrict__ ghist, const int* __restrict__ btot,
    unsigned* __restrict__ tmp, int n_edges, int nbins)
{
    __shared__ int lcur[1024];
    for (int i = threadIdx.x; i < nbins; i += 256)
        lcur[i] = ghist[i * NSB + blockIdx.x] + btot[i];
    __syncthreads();
    const int per = (n_edges + gridDim.x - 1) / gridDim.x;
    const int e0 = blockIdx.x * per;
    const int e1 = min(e0 + per, n_edges);
    for (int e = e0 + threadIdx.x; e < e1; e += 256) {
        const int s = second[e];
        const int pos = atomicAdd(&lcur[s >> BIN_SHIFT], 1);
        tmp[pos] = (unsigned)first[e] | ((unsigned)(s & 127) << 20);
    }
}

__global__ __launch_bounds__(256) void binsortD_kernel(
    const unsigned* __restrict__ tmp, const int* __restrict__ btot,
    int* __restrict__ sfirst, int* __restrict__ row_ptr, int* __restrict__ ptot,
    int n_edges, int n_links, int nbins)
{
    __shared__ int ldeg[128];
    __shared__ int lpre[128];
    __shared__ int lcur[128];
    const int b = blockIdx.x;
    const int tid = threadIdx.x;
    const int lbase = b << BIN_SHIFT;
    const int nl = min(128, n_links - lbase);
    const int eb = btot[b];
    const int ee = (b + 1 < nbins) ? btot[b + 1] : n_edges;

    if (tid < 128) ldeg[tid] = 0;
    __syncthreads();
    for (int e = eb + tid; e < ee; e += 256)
        atomicAdd(&ldeg[tmp[e] >> 20], 1);
    __syncthreads();
    if (tid < 64) {
        const int d0 = ldeg[tid], d1 = ldeg[64 + tid];
        int p0 = d0, p1 = d1;
#pragma unroll
        for (int off = 1; off < 64; off <<= 1) {
            const int t0 = __shfl_up(p0, off, 64);
            const int t1 = __shfl_up(p1, off, 64);
            if (tid >= off) { p0 += t0; p1 += t1; }
        }
        const int tot0 = __shfl(p0, 63, 64);
        lpre[tid] = p0 - d0;
        lpre[64 + tid] = tot0 + p1 - d1;
        // padded tile-count total for this bin
        const int n0 = (d0 + 15) >> 4, n1 = (d1 + 15) >> 4;
        int q0 = n0, q1 = n1;
#pragma unroll
        for (int off = 1; off < 64; off <<= 1) {
            const int t0 = __shfl_up(q0, off, 64);
            const int t1 = __shfl_up(q1, off, 64);
            if (tid >= off) { q0 += t0; q1 += t1; }
        }
        if (tid == 63) ptot[b] = q0 + q1;
    }
    __syncthreads();
    if (tid < nl) row_ptr[lbase + tid] = eb + lpre[tid];
    if (b == nbins - 1 && tid == 0) row_ptr[n_links] = n_edges;
    if (tid < 128) lcur[tid] = lpre[tid];
    __syncthreads();
    for (int e = eb + tid; e < ee; e += 256) {
        const unsigned v = tmp[e];
        const int pos = eb + atomicAdd(&lcur[v >> 20], 1);
        sfirst[pos] = (int)(v & 0xFFFFFu);
    }
    if (b == 0)
        for (int i = tid; i < 64; i += 256) sfirst[n_edges + i] = 0;  // pipeline pad
}

// build per-tile descriptors: tinfo[t] = eo | li<<21 (3b) | last<<24 | vcnt<<25
// and per-link tile prefix ptile[l] (ptile[n_links] = total tiles)
// NOTE: tinfo aliases the (dead-after-binsortD) tmp buffer.
__global__ __launch_bounds__(256) void tbuild_kernel(
    const int* __restrict__ row_ptr, const int* __restrict__ tbase,
    int* __restrict__ ptile, int* __restrict__ tinfo,
    int n_links, int nbins)
{
    __shared__ int rpl[130];
    __shared__ int ltp[130];
    const int b = blockIdx.x, tid = threadIdx.x;
    const int lbase = b << BIN_SHIFT;
    const int nl = min(128, n_links - lbase);
    if (tid <= nl) rpl[tid] = row_ptr[lbase + tid];
    __syncthreads();
    if (tid < 64) {
        const int d0 = (tid < nl) ? rpl[tid + 1] - rpl[tid] : 0;
        const int d1 = (64 + tid < nl) ? rpl[64 + tid + 1] - rpl[64 + tid] : 0;
        const int n0 = (d0 + 15) >> 4, n1 = (d1 + 15) >> 4;
        int p0 = n0, p1 = n1;
#pragma unroll
        for (int off = 1; off < 64; off <<= 1) {
            const int t0 = __shfl_up(p0, off, 64);
            const int t1 = __shfl_up(p1, off, 64);
            if (tid >= off) { p0 += t0; p1 += t1; }
        }
        const int tot0 = __shfl(p0, 63, 64);
        ltp[tid] = p0 - n0;
        ltp[64 + tid] = tot0 + p1 - n1;
        if (tid == 63) ltp[128] = tot0 + p1;
    }
    __syncthreads();
    const int tb = tbase[b];
    if (tid <= nl) ptile[lbase + tid] = tb + ltp[tid];
    const int ntb = ltp[128];
    for (int tl = tid; tl < ntb; tl += 256) {
        int lo = 0, hi = nl - 1;
        while (lo < hi) {                      // largest li with ltp[li] <= tl
            const int mid = (lo + hi + 1) >> 1;
            if (ltp[mid] <= tl) lo = mid; else hi = mid - 1;
        }
        const int li = lo;
        const int eo = rpl[li] + ((tl - ltp[li]) << 4);
        const int rend = rpl[li + 1];
        const int vc = min(16, rend - eo);
        const int last = (eo + 16 >= rend) ? 1 : 0;
        tinfo[tb + tl] = eo | ((li & 7) << 21) | (last << 24) | (vc << 25);
    }
    if (b == nbins - 1 && tid < 8) tinfo[tb + ntb + tid] = 0;  // SENT pads (vcnt=0)
}

__global__ __launch_bounds__(256) void growfind_kernel(
    const int* __restrict__ gid, int* __restrict__ grow, int n_links, int G)
{
    const int g = blockIdx.x * blockDim.x + threadIdx.x;
    if (g > G) return;
    if (g == G) { grow[G] = n_links; return; }
    int lo = 0, hi = n_links;
    while (lo < hi) {
        const int mid = (lo + hi) >> 1;
        if (gid[mid] < g) lo = mid + 1; else hi = mid;
    }
    grow[g] = lo;
}

// ---------------- P via MFMA: bf16 state A (direct loads), split-B ----------
__global__ __launch_bounds__(256) void p_mfma_kernel(
    const unsigned short* __restrict__ Sb,
    const unsigned short* __restrict__ WAh, const unsigned short* __restrict__ WAl,
    unsigned short* __restrict__ P, int n_links)
{
    const int tid = threadIdx.x;
    const int wave = tid >> 6;
    const int lane = tid & 63;
    const int m = lane & 15;
    const int qd = lane >> 4;

    bf16x8 Bh[2][4], Bl[2][4];
#pragma unroll
    for (int ks = 0; ks < 2; ++ks)
#pragma unroll
        for (int jt = 0; jt < 4; ++jt) {
            const int off = FIDX(ks, jt, qd, m);
            Bh[ks][jt] = *(const bf16x8*)(WAh + off);
            Bl[ks][jt] = *(const bf16x8*)(WAl + off);
        }
    const bf16x8 z = (bf16x8){0, 0, 0, 0, 0, 0, 0, 0};

    const int ngroups = (n_links + 63) >> 6;
    for (int g = blockIdx.x; g < ngroups; g += gridDim.x) {
        const int base = g * 64 + wave * 16;
        const int l = base + m;
        bf16x8 Ah0 = z, Ah1 = z;
        if (l < n_links) {
            Ah0 = *(const bf16x8*)(Sb + (size_t)l * D + qd * 8);
            Ah1 = *(const bf16x8*)(Sb + (size_t)l * D + 32 + qd * 8);
        }
        f32x4 accP[4];
#pragma unroll
        for (int jt = 0; jt < 4; ++jt) {
            accP[jt] = (f32x4){0.f, 0.f, 0.f, 0.f};
            accP[jt] = __builtin_amdgcn_mfma_f32_16x16x32_bf16(Ah0, Bh[0][jt], accP[jt], 0, 0, 0);
            accP[jt] = __builtin_amdgcn_mfma_f32_16x16x32_bf16(Ah0, Bl[0][jt], accP[jt], 0, 0, 0);
            accP[jt] = __builtin_amdgcn_mfma_f32_16x16x32_bf16(Ah1, Bh[1][jt], accP[jt], 0, 0, 0);
            accP[jt] = __builtin_amdgcn_mfma_f32_16x16x32_bf16(Ah1, Bl[1][jt], accP[jt], 0, 0, 0);
        }
#pragma unroll
        for (int r = 0; r < 4; ++r) {
            const int lr = base + qd * 4 + r;
            if (lr < n_links) {
#pragma unroll
                for (int jt = 0; jt < 4; ++jt)
                    P[(size_t)lr * D + jt * 16 + m] =
                        (unsigned short)f2bf_rtne(accP[jt][r]);
            }
        }
    }
}

// ---------------- link-centric fused edge kernel (tinfo-driven) -------------
// Round 8: revert CHUNK to 8 (round-5 measured best; CHUNK=16's 1.5-batch
// wave count hurt occupancy 40->33). Round-5 body + qli Q-cache: ~32% of
// tiles repeat the previous link -> skip the 4 ds_read_b128 qt re-reads.
// Keeps (256,4) GPR cap (4-wave band; next quantum at 64 total is infeasible).
__global__ __launch_bounds__(256, 4) void edge_link_kernel(
    unsigned short* __restrict__ Sb, const unsigned short* __restrict__ P,
    const int* __restrict__ sfirst, const int* __restrict__ tinfo,
    const int* __restrict__ ptile,
    const float* __restrict__ b_msg,
    const unsigned short* __restrict__ WBh, const unsigned short* __restrict__ WBl,
    const unsigned short* __restrict__ WGh,
    const float* __restrict__ b_gcn, const float* __restrict__ cstar,
    int n_links)
{
    __shared__ float qt[4][CHUNK * QSTRIDE + 4];
    __shared__ float cbl[64];
    const int tid = threadIdx.x;
    const int wave = tid >> 6;
    const int lane = tid & 63;
    const int m = lane & 15;
    const int qd = lane >> 4;

    // each wave writes the full cbl (benign identical-value race across waves)
    cbl[lane] = cstar[lane];

    const int l0 = (blockIdx.x * 4 + wave) * CHUNK;
    if (l0 >= n_links) return;
    const int nl = min(CHUNK, n_links - l0);

    const float LOG2E = 1.4426950408889634f;
    float bmsgC[4];
#pragma unroll
    for (int jt = 0; jt < 4; ++jt) bmsgC[jt] = b_msg[jt * 16 + m] * LOG2E;

    // ---- Phase 1: Q-tile from bf16 state chunk (A direct, pre-split B) ----
    {
        const bf16x8 z = (bf16x8){0, 0, 0, 0, 0, 0, 0, 0};
        const int l = l0 + m;
        bf16x8 Ah0 = z, Ah1 = z;
        if ((l < n_links) && (m < CHUNK)) {
            Ah0 = *(const bf16x8*)(Sb + (size_t)l * D + qd * 8);
            Ah1 = *(const bf16x8*)(Sb + (size_t)l * D + 32 + qd * 8);
        }
        f32x4 accQ[4];
#pragma unroll
        for (int jt = 0; jt < 4; ++jt) accQ[jt] = (f32x4){0.f, 0.f, 0.f, 0.f};
#pragma unroll
        for (int ks = 0; ks < 2; ++ks) {
            bf16x8 WbH[4], WbL[4];
#pragma unroll
            for (int jt = 0; jt < 4; ++jt) {
                const int off = FIDX(ks, jt, qd, m);
                WbH[jt] = *(const bf16x8*)(WBh + off);
                WbL[jt] = *(const bf16x8*)(WBl + off);
            }
            const bf16x8 A = ks ? Ah1 : Ah0;
#pragma unroll
            for (int jt = 0; jt < 4; ++jt) {
                accQ[jt] = __builtin_amdgcn_mfma_f32_16x16x32_bf16(A, WbH[jt], accQ[jt], 0, 0, 0);
                accQ[jt] = __builtin_amdgcn_mfma_f32_16x16x32_bf16(A, WbL[jt], accQ[jt], 0, 0, 0);
            }
        }
#pragma unroll
        for (int r = 0; r < 4; ++r) {
            const int row = qd * 4 + r;
            if (row < CHUNK) {
#pragma unroll
                for (int jt = 0; jt < 4; ++jt)
                    qt[wave][row * QSTRIDE + jt * 16 + m] = accQ[jt][r] + bmsgC[jt];
            }
        }
    }

    // ---- W_gcn B-frags + scalar bias ----
    bf16x8 Gh[2][4];
#pragma unroll
    for (int ks = 0; ks < 2; ++ks)
#pragma unroll
        for (int jt = 0; jt < 4; ++jt)
            Gh[ks][jt] = *(const bf16x8*)(WGh + FIDX(ks, jt, qd, m));

    float bias_gcn[4];
#pragma unroll
    for (int jt = 0; jt < 4; ++jt) bias_gcn[jt] = b_gcn[jt * 16 + m];

    // ---- tile range for this chunk + zero empty links ----
    const int tpv = ptile[l0 + min(lane, nl)];
#pragma unroll
    for (int i = 0; i < CHUNK; ++i) {
        if (i < nl && __shfl(tpv, i + 1, 64) == __shfl(tpv, i, 64))
            Sb[(size_t)(l0 + i) * D + lane] = 0;
    }
    const int tbeg = __builtin_amdgcn_readfirstlane(tpv);
    const int tend = __builtin_amdgcn_readfirstlane(__shfl(tpv, nl, 64));
    if (tbeg >= tend) return;

    // ---- pipeline prologue: tinfo 3 deep, sf 1 deep, p current ----
    int ti0 = tinfo[tbeg];
    int ti1 = tinfo[tbeg + 1];
    int ti2 = tinfo[tbeg + 2];

    bf16x8 p00, p01;
    {
        const int eo = ti0 & 0x1FFFFF, vc = (ti0 >> 25) & 31;
        int sf = sfirst[eo + m];
        sf = (m < vc) ? sf : n_links;
        const unsigned short* Pr = P + (size_t)sf * D;
        p00 = *(const bf16x8*)(Pr + qd * 8);
        p01 = *(const bf16x8*)(Pr + 32 + qd * 8);
    }
    int sf1;
    {
        const int eo = ti1 & 0x1FFFFF, vc = (ti1 >> 25) & 31;
        int sf = sfirst[eo + m];
        sf1 = (m < vc) ? sf : n_links;
    }

    float qb[16];
    int qli = -1;
    float rsum[4] = {0.f, 0.f, 0.f, 0.f};

    for (int t = tbeg; t < tend; ++t) {
        const int tiN = tinfo[t + 3];                 // padded past global end
        // sf for t+2
        const int eo2 = ti2 & 0x1FFFFF, vc2 = (ti2 >> 25) & 31;
        int sf2 = sfirst[eo2 + m];
        sf2 = (m < vc2) ? sf2 : n_links;
        // p for t+1
        const unsigned short* Pr1 = P + (size_t)sf1 * D;
        const bf16x8 p10 = *(const bf16x8*)(Pr1 + qd * 8);
        const bf16x8 p11 = *(const bf16x8*)(Pr1 + 32 + qd * 8);

        const int li0 = (ti0 >> 21) & 7;
        const int vc0 = (ti0 >> 25) & 31;

        if (li0 != qli) {                             // wave-uniform branch
            qli = li0;
            const int qoff = li0 * QSTRIDE + qd * 8;
            *(float4*)&qb[0]  = *(const float4*)&qt[wave][qoff];
            *(float4*)&qb[4]  = *(const float4*)&qt[wave][qoff + 4];
            *(float4*)&qb[8]  = *(const float4*)&qt[wave][qoff + 32];
            *(float4*)&qb[12] = *(const float4*)&qt[wave][qoff + 36];
        }

        // half A: selu, pack
        float msgA[8];
#pragma unroll
        for (int i = 0; i < 8; ++i)
            msgA[i] = selu_x2(bf2f(p00[i]) + qb[i]);
        const bf16x8 Ah0 = pack8(msgA);
        // half B
        float msgB[8];
#pragma unroll
        for (int i = 0; i < 8; ++i)
            msgB[i] = selu_x2(bf2f(p01[i]) + qb[8 + i]);
        const bf16x8 Ah1 = pack8(msgB);

        f32x4 acc[4];
#pragma unroll
        for (int jt = 0; jt < 4; ++jt) {
            const float b = bias_gcn[jt];
            acc[jt] = (f32x4){b, b, b, b};
            acc[jt] = __builtin_amdgcn_mfma_f32_16x16x32_bf16(Ah0, Gh[0][jt], acc[jt], 0, 0, 0);
            acc[jt] = __builtin_amdgcn_mfma_f32_16x16x32_bf16(Ah1, Gh[1][jt], acc[jt], 0, 0, 0);
        }
#pragma unroll
        for (int jt = 0; jt < 4; ++jt)
#pragma unroll
            for (int r = 0; r < 4; ++r)
                rsum[jt] += fmaxf(acc[jt][r], 0.0f);

        if (ti0 & (1 << 24)) {                        // last tile of link li0
            const int over = qd * 4 + 4 - vc0;        // invalid rows in this qd group
            const float cnt = (float)max(0, min(4, over));
#pragma unroll
            for (int jt = 0; jt < 4; ++jt) {
                rsum[jt] -= cbl[jt * 16 + m] * cnt;
                rsum[jt] += __shfl_xor(rsum[jt], 16, 64);
                rsum[jt] += __shfl_xor(rsum[jt], 32, 64);
            }
            const float outv = (qd == 0) ? rsum[0] : (qd == 1) ? rsum[1]
                             : (qd == 2) ? rsum[2] : rsum[3];
            Sb[(size_t)(l0 + li0) * D + lane] = (unsigned short)f2bf_rtne(outv);
#pragma unroll
            for (int jt = 0; jt < 4; ++jt) rsum[jt] = 0.0f;
        }

        ti0 = ti1; ti1 = ti2; ti2 = tiN;
        sf1 = sf2;
        p00 = p10; p01 = p11;
    }
}

// ---------------- readout: parallel segment-sum (bf16 S) + tiny MLP ---------
__global__ __launch_bounds__(256) void gsum8_kernel(
    const unsigned short* __restrict__ Sb, const int* __restrict__ grow,
    float* __restrict__ gemb)
{
    __shared__ float red[4][64];
    const int g = blockIdx.x >> 3;
    const int slice = blockIdx.x & 7;
    const int slot = threadIdx.x >> 6;
    const int j = threadIdx.x & 63;
    const int ls = grow[g], le = grow[g + 1];
    float acc = 0.0f;
    for (int l = ls + slice * 4 + slot; l < le; l += 32)
        acc += bf2f((short)Sb[(size_t)l * D + j]);
    red[slot][j] = acc;
    __syncthreads();
    if (slot == 0)
        atomicAdd(&gemb[g * D + j], red[0][j] + red[1][j] + red[2][j] + red[3][j]);
}

__global__ __launch_bounds__(256) void mlp_kernel(
    const float* __restrict__ gemb,
    const float* __restrict__ W_r1, const float* __restrict__ b_r1,
    const float* __restrict__ W_r2, const float* __restrict__ b_r2,
    const float* __restrict__ W_r3, const float* __restrict__ b_r3,
    float* __restrict__ out)
{
    __shared__ float gl[64];
    __shared__ float row1[RU];
    __shared__ float row2[RU];
    __shared__ float fin[4];
    const int g = blockIdx.x;
    const int tid = threadIdx.x;
    const int slot = tid >> 6;
    const int lane = tid & 63;

    if (tid < 64) gl[tid] = gemb[g * D + tid];
    __syncthreads();

    float a1 = b_r1[tid];
#pragma unroll 8
    for (int k = 0; k < 64; ++k) a1 += gl[k] * W_r1[k * RU + tid];
    row1[tid] = selu_f(a1);
    __syncthreads();

    float a2 = b_r2[tid];
#pragma unroll 8
    for (int k = 0; k < RU; ++k) a2 += row1[k] * W_r2[k * RU + tid];
    row2[tid] = selu_f(a2);
    __syncthreads();

    float p = row2[tid] * W_r3[tid];
#pragma unroll
    for (int off = 32; off >= 1; off >>= 1)
        p += __shfl_down(p, off, 64);
    if (lane == 0) fin[slot] = p;
    __syncthreads();
    if (tid == 0)
        out[g] = fin[0] + fin[1] + fin[2] + fin[3] + b_r3[0];
}

extern "C" void kernel_launch(void* const* d_in, const int* in_sizes, int n_in,
                              void* d_out, int out_size, void* d_ws, size_t ws_size,
                              hipStream_t stream)
{
    const float* states_action = (const float*)d_in[0];
    const float* W_msg = (const float*)d_in[1];
    const float* b_msg = (const float*)d_in[2];
    const float* W_gcn = (const float*)d_in[3];
    const float* b_gcn = (const float*)d_in[4];
    const float* W_r1 = (const float*)d_in[5];
    const float* b_r1 = (const float*)d_in[6];
    const float* W_r2 = (const float*)d_in[7];
    const float* b_r2 = (const float*)d_in[8];
    const float* W_r3 = (const float*)d_in[9];
    const float* b_r3 = (const float*)d_in[10];
    const int* gid = (const int*)d_in[11];
    const int* first = (const int*)d_in[12];
    const int* second = (const int*)d_in[13];

    const int n_links = in_sizes[0] / D;     // 100000
    const int n_edges = in_sizes[12];        // 1600000
    const int G = out_size;                  // 256
    const int nbins = (n_links + 127) >> BIN_SHIFT;   // 782

    char* ws2 = (char*)d_ws;
    auto alloc = [&](size_t bytes) {
        char* p = ws2; ws2 += (bytes + 63) & ~(size_t)63; return p;
    };
    unsigned short* Sb = (unsigned short*)alloc((size_t)n_links * D * 2);       // 12.8 MB
    unsigned short* Pb = (unsigned short*)alloc((size_t)(n_links + 1) * D * 2); // 12.8 MB (+sentinel row)
    float* gemb = (float*)alloc((size_t)G * D * sizeof(float));
    int* row_ptr = (int*)alloc((size_t)(n_links + 1) * sizeof(int));
    int* grow = (int*)alloc((size_t)(G + 1) * sizeof(int));
    unsigned* tmp = (unsigned*)alloc((size_t)n_edges * sizeof(unsigned));       // 6.4 MB (reused as tinfo)
    int* sfirst = (int*)alloc((size_t)(n_edges + 64) * sizeof(int));            // 6.4 MB (ghist aliases head)
    unsigned short* WAh = (unsigned short*)alloc(4096 * 2);
    unsigned short* WAl = (unsigned short*)alloc(4096 * 2);
    unsigned short* WBh = (unsigned short*)alloc(4096 * 2);
    unsigned short* WBl = (unsigned short*)alloc(4096 * 2);
    unsigned short* WGh = (unsigned short*)alloc(4096 * 2);
    int* btot = (int*)alloc((size_t)nbins * sizeof(int));
    int* ptotv = (int*)alloc((size_t)nbins * sizeof(int));
    int* ptile = (int*)alloc((size_t)(n_links + 1) * sizeof(int));
    float* cstar = (float*)alloc(64 * sizeof(float));
    // tinfo aliases tmp: tmp is dead after binsortD_kernel; tbuild_kernel runs
    // strictly later on the same stream. Max tiles = E/16 + L = 200000 (+8 pad).
    int* tinfoA = (int*)tmp;
    // ghist aliases sfirst: ghist live histA..scatterC; sfirst written only by
    // binsortD (strictly after scatterC). nbins*NSB = 200192 ints <= 6.4 MB.
    int* ghist = (int*)sfirst;

    // ---- input conversion + weight prep + atomic-free CSR build ----
    hipMemsetAsync(gemb, 0, (size_t)G * D * sizeof(float), stream);
    s2bf_kernel<<<1024, 256, 0, stream>>>(states_action, Sb, n_links * D / 4);
    wprep_kernel<<<16, 256, 0, stream>>>(W_msg, W_gcn, b_gcn, WAh, WAl, WBh, WBl,
                                         WGh, cstar, Pb, n_links);
    histA_kernel<<<NSB, 256, 0, stream>>>(second, ghist, n_edges, nbins);
    sumbins_kernel<<<nbins, 64, 0, stream>>>(ghist, btot, nbins);
    scanS_kernel<<<1, 1024, 0, stream>>>(btot, nbins);
    scatterC_kernel<<<NSB, 256, 0, stream>>>(first, second, ghist, btot, tmp,
                                             n_edges, nbins);
    binsortD_kernel<<<nbins, 256, 0, stream>>>(tmp, btot, sfirst, row_ptr, ptotv,
                                               n_edges, n_links, nbins);
    scanS_kernel<<<1, 1024, 0, stream>>>(ptotv, nbins);
    tbuild_kernel<<<nbins, 256, 0, stream>>>(row_ptr, ptotv, ptile, tinfoA,
                                             n_links, nbins);
    growfind_kernel<<<2, 256, 0, stream>>>(gid, grow, n_links, G);

    // ---- T = 4 message-passing iterations (state lives in Sb, bf16) ----
    const int edge_blocks = (n_links + 4 * CHUNK - 1) / (4 * CHUNK);  // 3125
    for (int t = 0; t < 4; ++t) {
        p_mfma_kernel<<<1024, 256, 0, stream>>>(Sb, WAh, WAl, Pb, n_links);
        edge_link_kernel<<<edge_blocks, 256, 0, stream>>>(Sb, Pb, sfirst, tinfoA,
                                                          ptile, b_msg, WBh, WBl,
                                                          WGh, b_gcn, cstar,
                                                          n_links);
    }

    // ---- readout ----
    gsum8_kernel<<<G * 8, 256, 0, stream>>>(Sb, grow, gemb);
    mlp_kernel<<<G, 256, 0, stream>>>(gemb, W_r1, b_r1, W_r2, b_r2,
                                      W_r3, b_r3, (float*)d_out);
}

// Round 10
// 477.360 us; speedup vs baseline: 1.1510x; 1.0930x over previous
//
#include <hip/hip_runtime.h>
#include <hip/hip_bf16.h>
#include <math.h>

#define D 64
#define RU 256
#define CHUNK 8
#define QSTRIDE 68
#define BIN_SHIFT 7          // 128 links per coarse bin
#define NSB 256              // setup blocks for histA/scatterC

#if __has_builtin(__builtin_amdgcn_exp2f)
#define EXP2F(x) __builtin_amdgcn_exp2f(x)
#else
#define EXP2F(x) exp2f(x)
#endif

typedef short bf16x8 __attribute__((ext_vector_type(8)));
typedef float f32x4 __attribute__((ext_vector_type(4)));

__device__ __forceinline__ float selu_f(float x) {
    return x > 0.0f ? 1.0507009873554805f * x
                    : 1.7580993408473766f * (__expf(x) - 1.0f);
}

// input pre-scaled by log2(e): x2 = log2e * x. selu(x) =
// 1.7581*exp2(min(x2,0)) + (1.0507*ln2)*max(x2,0) - 1.7581
__device__ __forceinline__ float selu_x2(float x2) {
    const float p = fmaxf(x2, 0.0f);
    const float n = fminf(x2, 0.0f);
    const float e = EXP2F(n);
    return fmaf(1.7580993408473766f, e, fmaf(0.72829042516f, p, -1.7580993408473766f));
}

__device__ __forceinline__ short f2bf_rtne(float x) {
    union { float f; unsigned u; } v; v.f = x;
    unsigned r = (v.u + 0x7FFFu + ((v.u >> 16) & 1u)) >> 16;
    return (short)r;
}
__device__ __forceinline__ float bf2f(short s) {
    union { float f; unsigned u; } v; v.u = ((unsigned)(unsigned short)s) << 16;
    return v.f;
}
__device__ __forceinline__ unsigned packpair(float a, float b) {
    float2 p; p.x = a; p.y = b;
    __hip_bfloat162 hb = __float22bfloat162_rn(p);
    return *(unsigned*)&hb;
}

__device__ __forceinline__ bf16x8 pack8(const float* v) {
    union { bf16x8 v; unsigned u[4]; } H;
#pragma unroll
    for (int j = 0; j < 4; ++j) H.u[j] = packpair(v[2 * j], v[2 * j + 1]);
    return H.v;
}

// fragment layout index: element i of the (ks,jt) B-fragment for lane (qd,m)
#define FIDX(ks, jt, qd, m) ((((((ks) * 4 + (jt)) * 4 + (qd)) * 16) + (m)) * 8)

// ================= one-shot weight fragment prep (fp32 -> bf16 hi/lo) =======
__global__ __launch_bounds__(256) void wprep_kernel(
    const float* __restrict__ W_msg, const float* __restrict__ W_gcn,
    unsigned short* __restrict__ WAh, unsigned short* __restrict__ WAl,
    unsigned short* __restrict__ WBh, unsigned short* __restrict__ WBl,
    unsigned short* __restrict__ WGh)
{
    const float LOG2E = 1.4426950408889634f;
    const int t = blockIdx.x * 256 + threadIdx.x;
    if (t >= 4096) return;
    const int i  = t & 7;
    const int m  = (t >> 3) & 15;
    const int qd = (t >> 7) & 3;
    const int jt = (t >> 9) & 3;
    const int ks = t >> 11;
    const int kk = ks * 32 + qd * 8 + i;
    const int nn = jt * 16 + m;

    float w = W_msg[kk * 64 + nn] * LOG2E;
    short hi = f2bf_rtne(w);
    WAh[t] = (unsigned short)hi;
    WAl[t] = (unsigned short)f2bf_rtne(w - bf2f(hi));

    w = W_msg[(64 + kk) * 64 + nn] * LOG2E;
    hi = f2bf_rtne(w);
    WBh[t] = (unsigned short)hi;
    WBl[t] = (unsigned short)f2bf_rtne(w - bf2f(hi));

    WGh[t] = (unsigned short)f2bf_rtne(W_gcn[kk * 64 + nn]);
}

// ================= input conversion: fp32 state -> bf16 =================
__global__ __launch_bounds__(256) void s2bf_kernel(
    const float* __restrict__ in, unsigned short* __restrict__ out, int n4)
{
    for (int i = blockIdx.x * 256 + threadIdx.x; i < n4; i += gridDim.x * 256) {
        const float4 v = ((const float4*)in)[i];
        uint2 o;
        o.x = packpair(v.x, v.y);
        o.y = packpair(v.z, v.w);
        ((uint2*)out)[i] = o;
    }
}

// ================= atomic-free CSR build (hierarchical scans) ===============

__global__ __launch_bounds__(256) void histA_kernel(
    const int* __restrict__ second, int* __restrict__ ghist,
    int n_edges, int nbins)
{
    __shared__ int lhist[1024];
    for (int i = threadIdx.x; i < nbins; i += 256) lhist[i] = 0;
    __syncthreads();
    const int per = (n_edges + gridDim.x - 1) / gridDim.x;
    const int e0 = blockIdx.x * per;
    const int e1 = min(e0 + per, n_edges);
    for (int e = e0 + threadIdx.x; e < e1; e += 256)
        atomicAdd(&lhist[second[e] >> BIN_SHIFT], 1);
    __syncthreads();
    for (int i = threadIdx.x; i < nbins; i += 256)
        ghist[i * gridDim.x + blockIdx.x] = lhist[i];
}

// per-bin: exclusive scan of the NSB=256 per-block counters (in place) + bin total
__global__ __launch_bounds__(64) void sumbins_kernel(
    int* __restrict__ ghist, int* __restrict__ btot, int nbins)
{
    const int b = blockIdx.x, tid = threadIdx.x;
    int d[4], p[4];
#pragma unroll
    for (int k = 0; k < 4; ++k) {
        d[k] = ghist[b * NSB + k * 64 + tid];
        p[k] = d[k];
    }
#pragma unroll
    for (int off = 1; off < 64; off <<= 1) {
#pragma unroll
        for (int k = 0; k < 4; ++k) {
            const int t = __shfl_up(p[k], off, 64);
            if (tid >= off) p[k] += t;
        }
    }
    int base = 0;
#pragma unroll
    for (int k = 0; k < 4; ++k) {
        const int tot = __shfl(p[k], 63, 64);
        ghist[b * NSB + k * 64 + tid] = base + p[k] - d[k];
        base += tot;
    }
    if (tid == 63) btot[b] = base;
}

// single-block exclusive scan, n <= 1024, in place
__global__ __launch_bounds__(1024) void scanS_kernel(int* __restrict__ data, int n)
{
    __shared__ int wsum[16], woff[16];
    const int tid = threadIdx.x, wave = tid >> 6, lane = tid & 63;
    const int x = (tid < n) ? data[tid] : 0;
    int v = x;
#pragma unroll
    for (int off = 1; off < 64; off <<= 1) {
        const int t = __shfl_up(v, off, 64);
        if (lane >= off) v += t;
    }
    if (lane == 63) wsum[wave] = v;
    __syncthreads();
    if (wave == 0) {
        int s = (lane < 16) ? wsum[lane] : 0;
#pragma unroll
        for (int off = 1; off < 16; off <<= 1) {
            const int t = __shfl_up(s, off, 64);
            if (lane >= off) s += t;
        }
        if (lane < 16) woff[lane] = s - wsum[lane];
    }
    __syncthreads();
    if (tid < n) data[tid] = woff[wave] + v - x;
}

// packed tmp: bits [0,20) = first, bits [20,27) = second & 127
__global__ __launch_bounds__(256) void scatterC_kernel(
    const int* __restrict__ first, const int* __restrict__ second,
    const int* __restrict__ ghist, const int* __restrict__ btot,
    unsigned* __restrict__ tmp, int n_edges, int nbins)
{
    __shared__ int lcur[1024];
    for (int i = threadIdx.x; i < nbins; i += 256)
        lcur[i] = ghist[i * NSB + blockIdx.x] + btot[i];
    __syncthreads();
    const int per = (n_edges + gridDim.x - 1) / gridDim.x;
    const int e0 = blockIdx.x * per;
    const int e1 = min(e0 + per, n_edges);
    for (int e = e0 + threadIdx.x; e < e1; e += 256) {
        const int s = second[e];
        const int pos = atomicAdd(&lcur[s >> BIN_SHIFT], 1);
        tmp[pos] = (unsigned)first[e] | ((unsigned)(s & 127) << 20);
    }
}

// sfirst: bits [0,20) = first, bits [20,23) = link & 7 (chunk-local li)
__global__ __launch_bounds__(256) void binsortD_kernel(
    const unsigned* __restrict__ tmp, const int* __restrict__ btot,
    int* __restrict__ sfirst, int* __restrict__ row_ptr,
    int n_edges, int n_links, int nbins)
{
    __shared__ int ldeg[128];
    __shared__ int lpre[128];
    __shared__ int lcur[128];
    const int b = blockIdx.x;
    const int tid = threadIdx.x;
    const int lbase = b << BIN_SHIFT;
    const int nl = min(128, n_links - lbase);
    const int eb = btot[b];
    const int ee = (b + 1 < nbins) ? btot[b + 1] : n_edges;

    if (tid < 128) ldeg[tid] = 0;
    __syncthreads();
    for (int e = eb + tid; e < ee; e += 256)
        atomicAdd(&ldeg[tmp[e] >> 20], 1);
    __syncthreads();
    if (tid < 64) {
        const int d0 = ldeg[tid], d1 = ldeg[64 + tid];
        int p0 = d0, p1 = d1;
#pragma unroll
        for (int off = 1; off < 64; off <<= 1) {
            const int t0 = __shfl_up(p0, off, 64);
            const int t1 = __shfl_up(p1, off, 64);
            if (tid >= off) { p0 += t0; p1 += t1; }
        }
        const int tot0 = __shfl(p0, 63, 64);
        lpre[tid] = p0 - d0;
        lpre[64 + tid] = tot0 + p1 - d1;
    }
    __syncthreads();
    if (tid < nl) row_ptr[lbase + tid] = eb + lpre[tid];
    if (b == nbins - 1 && tid == 0) row_ptr[n_links] = n_edges;
    if (tid < 128) lcur[tid] = lpre[tid];
    __syncthreads();
    for (int e = eb + tid; e < ee; e += 256) {
        const unsigned v = tmp[e];
        const int pos = eb + atomicAdd(&lcur[v >> 20], 1);
        sfirst[pos] = (int)(v & 0x7FFFFFu);   // first | (li&7)<<20
    }
    if (b == 0)
        for (int i = tid; i < 64; i += 256) sfirst[n_edges + i] = 0;  // pipeline pad
}

__global__ __launch_bounds__(256) void growfind_kernel(
    const int* __restrict__ gid, int* __restrict__ grow, int n_links, int G)
{
    const int g = blockIdx.x * blockDim.x + threadIdx.x;
    if (g > G) return;
    if (g == G) { grow[G] = n_links; return; }
    int lo = 0, hi = n_links;
    while (lo < hi) {
        const int mid = (lo + hi) >> 1;
        if (gid[mid] < g) lo = mid + 1; else hi = mid;
    }
    grow[g] = lo;
}

// ---------------- P via MFMA: bf16 state A (direct loads), split-B ----------
__global__ __launch_bounds__(256) void p_mfma_kernel(
    const unsigned short* __restrict__ Sb,
    const unsigned short* __restrict__ WAh, const unsigned short* __restrict__ WAl,
    unsigned short* __restrict__ P, int n_links)
{
    const int tid = threadIdx.x;
    const int wave = tid >> 6;
    const int lane = tid & 63;
    const int m = lane & 15;
    const int qd = lane >> 4;

    bf16x8 Bh[2][4], Bl[2][4];
#pragma unroll
    for (int ks = 0; ks < 2; ++ks)
#pragma unroll
        for (int jt = 0; jt < 4; ++jt) {
            const int off = FIDX(ks, jt, qd, m);
            Bh[ks][jt] = *(const bf16x8*)(WAh + off);
            Bl[ks][jt] = *(const bf16x8*)(WAl + off);
        }
    const bf16x8 z = (bf16x8){0, 0, 0, 0, 0, 0, 0, 0};

    const int ngroups = (n_links + 63) >> 6;
    for (int g = blockIdx.x; g < ngroups; g += gridDim.x) {
        const int base = g * 64 + wave * 16;
        const int l = base + m;
        bf16x8 Ah0 = z, Ah1 = z;
        if (l < n_links) {
            Ah0 = *(const bf16x8*)(Sb + (size_t)l * D + qd * 8);
            Ah1 = *(const bf16x8*)(Sb + (size_t)l * D + 32 + qd * 8);
        }
        f32x4 accP[4];
#pragma unroll
        for (int jt = 0; jt < 4; ++jt) {
            accP[jt] = (f32x4){0.f, 0.f, 0.f, 0.f};
            accP[jt] = __builtin_amdgcn_mfma_f32_16x16x32_bf16(Ah0, Bh[0][jt], accP[jt], 0, 0, 0);
            accP[jt] = __builtin_amdgcn_mfma_f32_16x16x32_bf16(Ah0, Bl[0][jt], accP[jt], 0, 0, 0);
            accP[jt] = __builtin_amdgcn_mfma_f32_16x16x32_bf16(Ah1, Bh[1][jt], accP[jt], 0, 0, 0);
            accP[jt] = __builtin_amdgcn_mfma_f32_16x16x32_bf16(Ah1, Bl[1][jt], accP[jt], 0, 0, 0);
        }
#pragma unroll
        for (int r = 0; r < 4; ++r) {
            const int lr = base + qd * 4 + r;
            if (lr < n_links) {
#pragma unroll
                for (int jt = 0; jt < 4; ++jt)
                    P[(size_t)lr * D + jt * 16 + m] =
                        (unsigned short)f2bf_rtne(accP[jt][r]);
            }
        }
    }
}

// ---------------- link-centric fused edge kernel (DENSE tiles) --------------
// Round 9: dense tiles over the chunk's contiguous edge stream (no per-link
// 16-padding: ~8.04 tiles/chunk vs 11.7). Per-edge chunk-local link id (3b)
// rides in sfirst bits [20,23). Segmented reduction: wave-uniform bcur walks
// links; rows accumulate via li-mask; link finishes when row_ptr[b+1] <=
// eo+16. Tail rows get li=8 (never match) -> no sentinel/cstar machinery.
// Empty links finish naturally with rsum=0. tinfo/tbuild/ptile all removed.
__global__ __launch_bounds__(256, 4) void edge_link_kernel(
    unsigned short* __restrict__ Sb, const unsigned short* __restrict__ P,
    const int* __restrict__ sfirst, const int* __restrict__ row_ptr,
    const float* __restrict__ b_msg,
    const unsigned short* __restrict__ WBh, const unsigned short* __restrict__ WBl,
    const unsigned short* __restrict__ WGh,
    const float* __restrict__ b_gcn,
    int n_links)
{
    __shared__ float qt[4][CHUNK * QSTRIDE + 4];
    const int tid = threadIdx.x;
    const int wave = tid >> 6;
    const int lane = tid & 63;
    const int m = lane & 15;
    const int qd = lane >> 4;

    const int l0 = (blockIdx.x * 4 + wave) * CHUNK;
    if (l0 >= n_links) return;
    const int nl = min(CHUNK, n_links - l0);

    const float LOG2E = 1.4426950408889634f;
    float bmsgC[4];
#pragma unroll
    for (int jt = 0; jt < 4; ++jt) bmsgC[jt] = b_msg[jt * 16 + m] * LOG2E;

    // ---- Phase 1: Q-tile from bf16 state chunk (A direct, pre-split B) ----
    {
        const bf16x8 z = (bf16x8){0, 0, 0, 0, 0, 0, 0, 0};
        const int l = l0 + m;
        bf16x8 Ah0 = z, Ah1 = z;
        if ((l < n_links) && (m < CHUNK)) {
            Ah0 = *(const bf16x8*)(Sb + (size_t)l * D + qd * 8);
            Ah1 = *(const bf16x8*)(Sb + (size_t)l * D + 32 + qd * 8);
        }
        f32x4 accQ[4];
#pragma unroll
        for (int jt = 0; jt < 4; ++jt) accQ[jt] = (f32x4){0.f, 0.f, 0.f, 0.f};
#pragma unroll
        for (int ks = 0; ks < 2; ++ks) {
            bf16x8 WbH[4], WbL[4];
#pragma unroll
            for (int jt = 0; jt < 4; ++jt) {
                const int off = FIDX(ks, jt, qd, m);
                WbH[jt] = *(const bf16x8*)(WBh + off);
                WbL[jt] = *(const bf16x8*)(WBl + off);
            }
            const bf16x8 A = ks ? Ah1 : Ah0;
#pragma unroll
            for (int jt = 0; jt < 4; ++jt) {
                accQ[jt] = __builtin_amdgcn_mfma_f32_16x16x32_bf16(A, WbH[jt], accQ[jt], 0, 0, 0);
                accQ[jt] = __builtin_amdgcn_mfma_f32_16x16x32_bf16(A, WbL[jt], accQ[jt], 0, 0, 0);
            }
        }
#pragma unroll
        for (int r = 0; r < 4; ++r) {
            const int row = qd * 4 + r;
            if (row < CHUNK) {
#pragma unroll
                for (int jt = 0; jt < 4; ++jt)
                    qt[wave][row * QSTRIDE + jt * 16 + m] = accQ[jt][r] + bmsgC[jt];
            }
        }
    }

    // ---- W_gcn B-frags + scalar bias ----
    bf16x8 Gh[2][4];
#pragma unroll
    for (int ks = 0; ks < 2; ++ks)
#pragma unroll
        for (int jt = 0; jt < 4; ++jt)
            Gh[ks][jt] = *(const bf16x8*)(WGh + FIDX(ks, jt, qd, m));

    float bias_gcn[4];
#pragma unroll
    for (int jt = 0; jt < 4; ++jt) bias_gcn[jt] = b_gcn[jt * 16 + m];

    // ---- chunk edge range ----
    const int rpv = row_ptr[l0 + min(lane, nl)];
#define RP(i) __shfl(rpv, (i), 64)
    const int eb = __builtin_amdgcn_readfirstlane(RP(0));
    const int ee = __builtin_amdgcn_readfirstlane(RP(nl));
    if (eb >= ee) {                       // whole chunk empty
        for (int i = 0; i < nl; ++i)
            Sb[(size_t)(l0 + i) * D + lane] = 0;
        return;
    }
    const int ntiles = (ee - eb + 15) >> 4;

    // ---- prologue: sv 2 deep, p current ----
    int sv0 = sfirst[eb + m];
    int sv1 = sfirst[eb + 16 + m];
    bf16x8 p00, p01;
    {
        const unsigned short* Pr = P + (size_t)(sv0 & 0xFFFFF) * D;
        p00 = *(const bf16x8*)(Pr + qd * 8);
        p01 = *(const bf16x8*)(Pr + 32 + qd * 8);
    }

    int bcur = 0;
    float rsum[4] = {0.f, 0.f, 0.f, 0.f};
    int eo = eb;

    for (int t = 0; t < ntiles; ++t, eo += 16) {
        // sv for t+2
        const int sv2 = sfirst[eo + 32 + m];
        // p for t+1
        const unsigned short* Pr1 = P + (size_t)(sv1 & 0xFFFFF) * D;
        const bf16x8 p10 = *(const bf16x8*)(Pr1 + qd * 8);
        const bf16x8 p11 = *(const bf16x8*)(Pr1 + 32 + qd * 8);

        // per-lane link id for this tile's gather column (edge eo+m)
        const bool valid = (eo + m < ee);
        const int limv = valid ? ((sv0 >> 20) & 7) : 8;
        const int qoff = (valid ? ((sv0 >> 20) & 7) : 0) * QSTRIDE + qd * 8;

        // Q re-read (per-lane address; same-li lanes broadcast)
        float qb[16];
        *(float4*)&qb[0]  = *(const float4*)&qt[wave][qoff];
        *(float4*)&qb[4]  = *(const float4*)&qt[wave][qoff + 4];
        *(float4*)&qb[8]  = *(const float4*)&qt[wave][qoff + 32];
        *(float4*)&qb[12] = *(const float4*)&qt[wave][qoff + 36];

        // selu + pack
        float msgA[8];
#pragma unroll
        for (int i = 0; i < 8; ++i)
            msgA[i] = selu_x2(bf2f(p00[i]) + qb[i]);
        const bf16x8 Ah0 = pack8(msgA);
        float msgB[8];
#pragma unroll
        for (int i = 0; i < 8; ++i)
            msgB[i] = selu_x2(bf2f(p01[i]) + qb[8 + i]);
        const bf16x8 Ah1 = pack8(msgB);

        f32x4 acc[4];
#pragma unroll
        for (int jt = 0; jt < 4; ++jt) {
            const float b = bias_gcn[jt];
            acc[jt] = (f32x4){b, b, b, b};
            acc[jt] = __builtin_amdgcn_mfma_f32_16x16x32_bf16(Ah0, Gh[0][jt], acc[jt], 0, 0, 0);
            acc[jt] = __builtin_amdgcn_mfma_f32_16x16x32_bf16(Ah1, Gh[1][jt], acc[jt], 0, 0, 0);
        }

        // link ids of this lane's rows (rows qd*4+r; li of edge eo+j is in lane j)
        const int lr0 = __shfl(limv, qd * 4 + 0, 64);
        const int lr1 = __shfl(limv, qd * 4 + 1, 64);
        const int lr2 = __shfl(limv, qd * 4 + 2, 64);
        const int lr3 = __shfl(limv, qd * 4 + 3, 64);

        // segmented accumulate / finish loop (wave-uniform control)
        while (true) {
            const int b0 = bcur;
#pragma unroll
            for (int jt = 0; jt < 4; ++jt) {
                rsum[jt] += fmaxf((lr0 == b0) ? acc[jt][0] : 0.0f, 0.0f);
                rsum[jt] += fmaxf((lr1 == b0) ? acc[jt][1] : 0.0f, 0.0f);
                rsum[jt] += fmaxf((lr2 == b0) ? acc[jt][2] : 0.0f, 0.0f);
                rsum[jt] += fmaxf((lr3 == b0) ? acc[jt][3] : 0.0f, 0.0f);
            }
            if (bcur < nl && RP(bcur + 1) <= eo + 16) {   // link b0 ends here
#pragma unroll
                for (int jt = 0; jt < 4; ++jt) {
                    rsum[jt] += __shfl_xor(rsum[jt], 16, 64);
                    rsum[jt] += __shfl_xor(rsum[jt], 32, 64);
                }
                const float outv = (qd == 0) ? rsum[0] : (qd == 1) ? rsum[1]
                                 : (qd == 2) ? rsum[2] : rsum[3];
                Sb[(size_t)(l0 + bcur) * D + lane] = (unsigned short)f2bf_rtne(outv);
#pragma unroll
                for (int jt = 0; jt < 4; ++jt) rsum[jt] = 0.0f;
                ++bcur;
                if (bcur >= nl) break;
            } else {
                break;
            }
        }

        sv0 = sv1; sv1 = sv2;
        p00 = p10; p01 = p11;
    }

    // defensive: any link not closed (should not happen) gets zeros
    while (bcur < nl) {
        Sb[(size_t)(l0 + bcur) * D + lane] = 0;
        ++bcur;
    }
#undef RP
}

// ---------------- readout: parallel segment-sum (bf16 S) + tiny MLP ---------
__global__ __launch_bounds__(256) void gsum8_kernel(
    const unsigned short* __restrict__ Sb, const int* __restrict__ grow,
    float* __restrict__ gemb)
{
    __shared__ float red[4][64];
    const int g = blockIdx.x >> 3;
    const int slice = blockIdx.x & 7;
    const int slot = threadIdx.x >> 6;
    const int j = threadIdx.x & 63;
    const int ls = grow[g], le = grow[g + 1];
    float acc = 0.0f;
    for (int l = ls + slice * 4 + slot; l < le; l += 32)
        acc += bf2f((short)Sb[(size_t)l * D + j]);
    red[slot][j] = acc;
    __syncthreads();
    if (slot == 0)
        atomicAdd(&gemb[g * D + j], red[0][j] + red[1][j] + red[2][j] + red[3][j]);
}

__global__ __launch_bounds__(256) void mlp_kernel(
    const float* __restrict__ gemb,
    const float* __restrict__ W_r1, const float* __restrict__ b_r1,
    const float* __restrict__ W_r2, const float* __restrict__ b_r2,
    const float* __restrict__ W_r3, const float* __restrict__ b_r3,
    float* __restrict__ out)
{
    __shared__ float gl[64];
    __shared__ float row1[RU];
    __shared__ float row2[RU];
    __shared__ float fin[4];
    const int g = blockIdx.x;
    const int tid = threadIdx.x;
    const int slot = tid >> 6;
    const int lane = tid & 63;

    if (tid < 64) gl[tid] = gemb[g * D + tid];
    __syncthreads();

    float a1 = b_r1[tid];
#pragma unroll 8
    for (int k = 0; k < 64; ++k) a1 += gl[k] * W_r1[k * RU + tid];
    row1[tid] = selu_f(a1);
    __syncthreads();

    float a2 = b_r2[tid];
#pragma unroll 8
    for (int k = 0; k < RU; ++k) a2 += row1[k] * W_r2[k * RU + tid];
    row2[tid] = selu_f(a2);
    __syncthreads();

    float p = row2[tid] * W_r3[tid];
#pragma unroll
    for (int off = 32; off >= 1; off >>= 1)
        p += __shfl_down(p, off, 64);
    if (lane == 0) fin[slot] = p;
    __syncthreads();
    if (tid == 0)
        out[g] = fin[0] + fin[1] + fin[2] + fin[3] + b_r3[0];
}

extern "C" void kernel_launch(void* const* d_in, const int* in_sizes, int n_in,
                              void* d_out, int out_size, void* d_ws, size_t ws_size,
                              hipStream_t stream)
{
    const float* states_action = (const float*)d_in[0];
    const float* W_msg = (const float*)d_in[1];
    const float* b_msg = (const float*)d_in[2];
    const float* W_gcn = (const float*)d_in[3];
    const float* b_gcn = (const float*)d_in[4];
    const float* W_r1 = (const float*)d_in[5];
    const float* b_r1 = (const float*)d_in[6];
    const float* W_r2 = (const float*)d_in[7];
    const float* b_r2 = (const float*)d_in[8];
    const float* W_r3 = (const float*)d_in[9];
    const float* b_r3 = (const float*)d_in[10];
    const int* gid = (const int*)d_in[11];
    const int* first = (const int*)d_in[12];
    const int* second = (const int*)d_in[13];

    const int n_links = in_sizes[0] / D;     // 100000
    const int n_edges = in_sizes[12];        // 1600000
    const int G = out_size;                  // 256
    const int nbins = (n_links + 127) >> BIN_SHIFT;   // 782

    char* ws2 = (char*)d_ws;
    auto alloc = [&](size_t bytes) {
        char* p = ws2; ws2 += (bytes + 63) & ~(size_t)63; return p;
    };
    unsigned short* Sb = (unsigned short*)alloc((size_t)n_links * D * 2);       // 12.8 MB
    unsigned short* Pb = (unsigned short*)alloc((size_t)n_links * D * 2);       // 12.8 MB
    float* gemb = (float*)alloc((size_t)G * D * sizeof(float));
    int* row_ptr = (int*)alloc((size_t)(n_links + 1) * sizeof(int));
    int* grow = (int*)alloc((size_t)(G + 1) * sizeof(int));
    unsigned* tmp = (unsigned*)alloc((size_t)n_edges * sizeof(unsigned));       // 6.4 MB
    int* sfirst = (int*)alloc((size_t)(n_edges + 64) * sizeof(int));            // 6.4 MB (ghist aliases head)
    unsigned short* WAh = (unsigned short*)alloc(4096 * 2);
    unsigned short* WAl = (unsigned short*)alloc(4096 * 2);
    unsigned short* WBh = (unsigned short*)alloc(4096 * 2);
    unsigned short* WBl = (unsigned short*)alloc(4096 * 2);
    unsigned short* WGh = (unsigned short*)alloc(4096 * 2);
    int* btot = (int*)alloc((size_t)nbins * sizeof(int));
    // ghist aliases sfirst: ghist live histA..scatterC; sfirst written only by
    // binsortD (strictly after scatterC). nbins*NSB = 200192 ints <= 6.4 MB.
    int* ghist = (int*)sfirst;

    // ---- input conversion + weight prep + atomic-free CSR build ----
    hipMemsetAsync(gemb, 0, (size_t)G * D * sizeof(float), stream);
    s2bf_kernel<<<1024, 256, 0, stream>>>(states_action, Sb, n_links * D / 4);
    wprep_kernel<<<16, 256, 0, stream>>>(W_msg, W_gcn, WAh, WAl, WBh, WBl, WGh);
    histA_kernel<<<NSB, 256, 0, stream>>>(second, ghist, n_edges, nbins);
    sumbins_kernel<<<nbins, 64, 0, stream>>>(ghist, btot, nbins);
    scanS_kernel<<<1, 1024, 0, stream>>>(btot, nbins);
    scatterC_kernel<<<NSB, 256, 0, stream>>>(first, second, ghist, btot, tmp,
                                             n_edges, nbins);
    binsortD_kernel<<<nbins, 256, 0, stream>>>(tmp, btot, sfirst, row_ptr,
                                               n_edges, n_links, nbins);
    growfind_kernel<<<2, 256, 0, stream>>>(gid, grow, n_links, G);

    // ---- T = 4 message-passing iterations (state lives in Sb, bf16) ----
    const int edge_blocks = (n_links + 4 * CHUNK - 1) / (4 * CHUNK);  // 3125
    for (int t = 0; t < 4; ++t) {
        p_mfma_kernel<<<1024, 256, 0, stream>>>(Sb, WAh, WAl, Pb, n_links);
        edge_link_kernel<<<edge_blocks, 256, 0, stream>>>(Sb, Pb, sfirst, row_ptr,
                                                          b_msg, WBh, WBl, WGh,
                                                          b_gcn, n_links);
    }

    // ---- readout ----
    gsum8_kernel<<<G * 8, 256, 0, stream>>>(Sb, grow, gemb);
    mlp_kernel<<<G, 256, 0, stream>>>(gemb, W_r1, b_r1, W_r2, b_r2,
                                      W_r3, b_r3, (float*)d_out);
}

// Round 11
// 448.918 us; speedup vs baseline: 1.2239x; 1.0634x over previous
//
#include <hip/hip_runtime.h>
#include <hip/hip_bf16.h>
#include <math.h>

#define D 64
#define RU 256
#define CHUNK 8
#define QSTRIDE 68
#define SSTRIDE 72           // srow stride (shorts): 144B rows -> 16B-aligned frags
#define BIN_SHIFT 7          // 128 links per coarse bin
#define NSB 256              // setup blocks for histA/scatterC

#if __has_builtin(__builtin_amdgcn_exp2f)
#define EXP2F(x) __builtin_amdgcn_exp2f(x)
#else
#define EXP2F(x) exp2f(x)
#endif

typedef short bf16x8 __attribute__((ext_vector_type(8)));
typedef float f32x4 __attribute__((ext_vector_type(4)));

__device__ __forceinline__ float selu_f(float x) {
    return x > 0.0f ? 1.0507009873554805f * x
                    : 1.7580993408473766f * (__expf(x) - 1.0f);
}

// input pre-scaled by log2(e): x2 = log2e * x. selu(x) =
// 1.7581*exp2(min(x2,0)) + (1.0507*ln2)*max(x2,0) - 1.7581
__device__ __forceinline__ float selu_x2(float x2) {
    const float p = fmaxf(x2, 0.0f);
    const float n = fminf(x2, 0.0f);
    const float e = EXP2F(n);
    return fmaf(1.7580993408473766f, e, fmaf(0.72829042516f, p, -1.7580993408473766f));
}

__device__ __forceinline__ short f2bf_rtne(float x) {
    union { float f; unsigned u; } v; v.f = x;
    unsigned r = (v.u + 0x7FFFu + ((v.u >> 16) & 1u)) >> 16;
    return (short)r;
}
__device__ __forceinline__ float bf2f(short s) {
    union { float f; unsigned u; } v; v.u = ((unsigned)(unsigned short)s) << 16;
    return v.f;
}
__device__ __forceinline__ unsigned packpair(float a, float b) {
    float2 p; p.x = a; p.y = b;
    __hip_bfloat162 hb = __float22bfloat162_rn(p);
    return *(unsigned*)&hb;
}

__device__ __forceinline__ bf16x8 pack8(const float* v) {
    union { bf16x8 v; unsigned u[4]; } H;
#pragma unroll
    for (int j = 0; j < 4; ++j) H.u[j] = packpair(v[2 * j], v[2 * j + 1]);
    return H.v;
}

// fragment layout index: element i of the (ks,jt) B-fragment for lane (qd,m)
#define FIDX(ks, jt, qd, m) ((((((ks) * 4 + (jt)) * 4 + (qd)) * 16) + (m)) * 8)

// ================= one-shot weight fragment prep (fp32 -> bf16 hi/lo) =======
__global__ __launch_bounds__(256) void wprep_kernel(
    const float* __restrict__ W_msg, const float* __restrict__ W_gcn,
    unsigned short* __restrict__ WAh, unsigned short* __restrict__ WAl,
    unsigned short* __restrict__ WBh, unsigned short* __restrict__ WBl,
    unsigned short* __restrict__ WGh)
{
    const float LOG2E = 1.4426950408889634f;
    const int t = blockIdx.x * 256 + threadIdx.x;
    if (t >= 4096) return;
    const int i  = t & 7;
    const int m  = (t >> 3) & 15;
    const int qd = (t >> 7) & 3;
    const int jt = (t >> 9) & 3;
    const int ks = t >> 11;
    const int kk = ks * 32 + qd * 8 + i;
    const int nn = jt * 16 + m;

    float w = W_msg[kk * 64 + nn] * LOG2E;
    short hi = f2bf_rtne(w);
    WAh[t] = (unsigned short)hi;
    WAl[t] = (unsigned short)f2bf_rtne(w - bf2f(hi));

    w = W_msg[(64 + kk) * 64 + nn] * LOG2E;
    hi = f2bf_rtne(w);
    WBh[t] = (unsigned short)hi;
    WBl[t] = (unsigned short)f2bf_rtne(w - bf2f(hi));

    WGh[t] = (unsigned short)f2bf_rtne(W_gcn[kk * 64 + nn]);
}

// ================= input conversion: fp32 state -> bf16 =================
__global__ __launch_bounds__(256) void s2bf_kernel(
    const float* __restrict__ in, unsigned short* __restrict__ out, int n4)
{
    for (int i = blockIdx.x * 256 + threadIdx.x; i < n4; i += gridDim.x * 256) {
        const float4 v = ((const float4*)in)[i];
        uint2 o;
        o.x = packpair(v.x, v.y);
        o.y = packpair(v.z, v.w);
        ((uint2*)out)[i] = o;
    }
}

// ================= atomic-free CSR build (hierarchical scans) ===============

__global__ __launch_bounds__(256) void histA_kernel(
    const int* __restrict__ second, int* __restrict__ ghist,
    int n_edges, int nbins)
{
    __shared__ int lhist[1024];
    for (int i = threadIdx.x; i < nbins; i += 256) lhist[i] = 0;
    __syncthreads();
    const int per = (n_edges + gridDim.x - 1) / gridDim.x;
    const int e0 = blockIdx.x * per;
    const int e1 = min(e0 + per, n_edges);
    for (int e = e0 + threadIdx.x; e < e1; e += 256)
        atomicAdd(&lhist[second[e] >> BIN_SHIFT], 1);
    __syncthreads();
    for (int i = threadIdx.x; i < nbins; i += 256)
        ghist[i * gridDim.x + blockIdx.x] = lhist[i];
}

// per-bin: exclusive scan of the NSB=256 per-block counters (in place) + bin total
__global__ __launch_bounds__(64) void sumbins_kernel(
    int* __restrict__ ghist, int* __restrict__ btot, int nbins)
{
    const int b = blockIdx.x, tid = threadIdx.x;
    int d[4], p[4];
#pragma unroll
    for (int k = 0; k < 4; ++k) {
        d[k] = ghist[b * NSB + k * 64 + tid];
        p[k] = d[k];
    }
#pragma unroll
    for (int off = 1; off < 64; off <<= 1) {
#pragma unroll
        for (int k = 0; k < 4; ++k) {
            const int t = __shfl_up(p[k], off, 64);
            if (tid >= off) p[k] += t;
        }
    }
    int base = 0;
#pragma unroll
    for (int k = 0; k < 4; ++k) {
        const int tot = __shfl(p[k], 63, 64);
        ghist[b * NSB + k * 64 + tid] = base + p[k] - d[k];
        base += tot;
    }
    if (tid == 63) btot[b] = base;
}

// single-block exclusive scan, n <= 1024, in place
__global__ __launch_bounds__(1024) void scanS_kernel(int* __restrict__ data, int n)
{
    __shared__ int wsum[16], woff[16];
    const int tid = threadIdx.x, wave = tid >> 6, lane = tid & 63;
    const int x = (tid < n) ? data[tid] : 0;
    int v = x;
#pragma unroll
    for (int off = 1; off < 64; off <<= 1) {
        const int t = __shfl_up(v, off, 64);
        if (lane >= off) v += t;
    }
    if (lane == 63) wsum[wave] = v;
    __syncthreads();
    if (wave == 0) {
        int s = (lane < 16) ? wsum[lane] : 0;
#pragma unroll
        for (int off = 1; off < 16; off <<= 1) {
            const int t = __shfl_up(s, off, 64);
            if (lane >= off) s += t;
        }
        if (lane < 16) woff[lane] = s - wsum[lane];
    }
    __syncthreads();
    if (tid < n) data[tid] = woff[wave] + v - x;
}

// packed tmp: bits [0,20) = first, bits [20,27) = second & 127
__global__ __launch_bounds__(256) void scatterC_kernel(
    const int* __restrict__ first, const int* __restrict__ second,
    const int* __restrict__ ghist, const int* __restrict__ btot,
    unsigned* __restrict__ tmp, int n_edges, int nbins)
{
    __shared__ int lcur[1024];
    for (int i = threadIdx.x; i < nbins; i += 256)
        lcur[i] = ghist[i * NSB + blockIdx.x] + btot[i];
    __syncthreads();
    const int per = (n_edges + gridDim.x - 1) / gridDim.x;
    const int e0 = blockIdx.x * per;
    const int e1 = min(e0 + per, n_edges);
    for (int e = e0 + threadIdx.x; e < e1; e += 256) {
        const int s = second[e];
        const int pos = atomicAdd(&lcur[s >> BIN_SHIFT], 1);
        tmp[pos] = (unsigned)first[e] | ((unsigned)(s & 127) << 20);
    }
}

// sfirst: bits [0,20) = first, bits [20,23) = link & 7 (chunk-local li)
__global__ __launch_bounds__(256) void binsortD_kernel(
    const unsigned* __restrict__ tmp, const int* __restrict__ btot,
    int* __restrict__ sfirst, int* __restrict__ row_ptr,
    int n_edges, int n_links, int nbins)
{
    __shared__ int ldeg[128];
    __shared__ int lpre[128];
    __shared__ int lcur[128];
    const int b = blockIdx.x;
    const int tid = threadIdx.x;
    const int lbase = b << BIN_SHIFT;
    const int nl = min(128, n_links - lbase);
    const int eb = btot[b];
    const int ee = (b + 1 < nbins) ? btot[b + 1] : n_edges;

    if (tid < 128) ldeg[tid] = 0;
    __syncthreads();
    for (int e = eb + tid; e < ee; e += 256)
        atomicAdd(&ldeg[tmp[e] >> 20], 1);
    __syncthreads();
    if (tid < 64) {
        const int d0 = ldeg[tid], d1 = ldeg[64 + tid];
        int p0 = d0, p1 = d1;
#pragma unroll
        for (int off = 1; off < 64; off <<= 1) {
            const int t0 = __shfl_up(p0, off, 64);
            const int t1 = __shfl_up(p1, off, 64);
            if (tid >= off) { p0 += t0; p1 += t1; }
        }
        const int tot0 = __shfl(p0, 63, 64);
        lpre[tid] = p0 - d0;
        lpre[64 + tid] = tot0 + p1 - d1;
    }
    __syncthreads();
    if (tid < nl) row_ptr[lbase + tid] = eb + lpre[tid];
    if (b == nbins - 1 && tid == 0) row_ptr[n_links] = n_edges;
    if (tid < 128) lcur[tid] = lpre[tid];
    __syncthreads();
    for (int e = eb + tid; e < ee; e += 256) {
        const unsigned v = tmp[e];
        const int pos = eb + atomicAdd(&lcur[v >> 20], 1);
        sfirst[pos] = (int)(v & 0x7FFFFFu);   // first | (li&7)<<20
    }
    if (b == 0)
        for (int i = tid; i < 64; i += 256) sfirst[n_edges + i] = 0;  // pipeline pad
}

__global__ __launch_bounds__(256) void growfind_kernel(
    const int* __restrict__ gid, int* __restrict__ grow, int n_links, int G)
{
    const int g = blockIdx.x * blockDim.x + threadIdx.x;
    if (g > G) return;
    if (g == G) { grow[G] = n_links; return; }
    int lo = 0, hi = n_links;
    while (lo < hi) {
        const int mid = (lo + hi) >> 1;
        if (gid[mid] < g) lo = mid + 1; else hi = mid;
    }
    grow[g] = lo;
}

// ---------------- P via MFMA: bf16 state A (direct loads), split-B ----------
__global__ __launch_bounds__(256) void p_mfma_kernel(
    const unsigned short* __restrict__ Sb,
    const unsigned short* __restrict__ WAh, const unsigned short* __restrict__ WAl,
    unsigned short* __restrict__ P, int n_links)
{
    const int tid = threadIdx.x;
    const int wave = tid >> 6;
    const int lane = tid & 63;
    const int m = lane & 15;
    const int qd = lane >> 4;

    bf16x8 Bh[2][4], Bl[2][4];
#pragma unroll
    for (int ks = 0; ks < 2; ++ks)
#pragma unroll
        for (int jt = 0; jt < 4; ++jt) {
            const int off = FIDX(ks, jt, qd, m);
            Bh[ks][jt] = *(const bf16x8*)(WAh + off);
            Bl[ks][jt] = *(const bf16x8*)(WAl + off);
        }
    const bf16x8 z = (bf16x8){0, 0, 0, 0, 0, 0, 0, 0};

    const int ngroups = (n_links + 63) >> 6;
    for (int g = blockIdx.x; g < ngroups; g += gridDim.x) {
        const int base = g * 64 + wave * 16;
        const int l = base + m;
        bf16x8 Ah0 = z, Ah1 = z;
        if (l < n_links) {
            Ah0 = *(const bf16x8*)(Sb + (size_t)l * D + qd * 8);
            Ah1 = *(const bf16x8*)(Sb + (size_t)l * D + 32 + qd * 8);
        }
        f32x4 accP[4];
#pragma unroll
        for (int jt = 0; jt < 4; ++jt) {
            accP[jt] = (f32x4){0.f, 0.f, 0.f, 0.f};
            accP[jt] = __builtin_amdgcn_mfma_f32_16x16x32_bf16(Ah0, Bh[0][jt], accP[jt], 0, 0, 0);
            accP[jt] = __builtin_amdgcn_mfma_f32_16x16x32_bf16(Ah0, Bl[0][jt], accP[jt], 0, 0, 0);
            accP[jt] = __builtin_amdgcn_mfma_f32_16x16x32_bf16(Ah1, Bh[1][jt], accP[jt], 0, 0, 0);
            accP[jt] = __builtin_amdgcn_mfma_f32_16x16x32_bf16(Ah1, Bl[1][jt], accP[jt], 0, 0, 0);
        }
#pragma unroll
        for (int r = 0; r < 4; ++r) {
            const int lr = base + qd * 4 + r;
            if (lr < n_links) {
#pragma unroll
                for (int jt = 0; jt < 4; ++jt)
                    P[(size_t)lr * D + jt * 16 + m] =
                        (unsigned short)f2bf_rtne(accP[jt][r]);
            }
        }
    }
}

// ---------------- link-centric fused edge kernel (DENSE tiles + P-tail) -----
// Round 10: fuse next-iteration P production into the tail. Finished S rows
// are stashed in per-wave LDS (srow, bf16, SSTRIDE=72 shorts -> 16B-aligned
// A-fragment reads, 2-way-bank-free) and the chunk's P(t+1) rows are computed
// with 16 MFMAs after the tile loop. Pout is a PING-PONG buffer (other blocks
// still gather P(t) from Pin). do_p=0 on the last iteration skips the tail.
__global__ __launch_bounds__(256, 4) void edge_link_kernel(
    unsigned short* __restrict__ Sb, const unsigned short* __restrict__ P,
    const int* __restrict__ sfirst, const int* __restrict__ row_ptr,
    const float* __restrict__ b_msg,
    const unsigned short* __restrict__ WBh, const unsigned short* __restrict__ WBl,
    const unsigned short* __restrict__ WGh,
    const float* __restrict__ b_gcn,
    const unsigned short* __restrict__ WAh, const unsigned short* __restrict__ WAl,
    unsigned short* __restrict__ Pout, int do_p,
    int n_links)
{
    __shared__ float qt[4][CHUNK * QSTRIDE + 4];
    __shared__ unsigned short srow[4][CHUNK * SSTRIDE];
    const int tid = threadIdx.x;
    const int wave = tid >> 6;
    const int lane = tid & 63;
    const int m = lane & 15;
    const int qd = lane >> 4;

    const int l0 = (blockIdx.x * 4 + wave) * CHUNK;
    if (l0 >= n_links) return;
    const int nl = min(CHUNK, n_links - l0);

    const float LOG2E = 1.4426950408889634f;
    float bmsgC[4];
#pragma unroll
    for (int jt = 0; jt < 4; ++jt) bmsgC[jt] = b_msg[jt * 16 + m] * LOG2E;

    // ---- Phase 1: Q-tile from bf16 state chunk (A direct, pre-split B) ----
    {
        const bf16x8 z = (bf16x8){0, 0, 0, 0, 0, 0, 0, 0};
        const int l = l0 + m;
        bf16x8 Ah0 = z, Ah1 = z;
        if ((l < n_links) && (m < CHUNK)) {
            Ah0 = *(const bf16x8*)(Sb + (size_t)l * D + qd * 8);
            Ah1 = *(const bf16x8*)(Sb + (size_t)l * D + 32 + qd * 8);
        }
        f32x4 accQ[4];
#pragma unroll
        for (int jt = 0; jt < 4; ++jt) accQ[jt] = (f32x4){0.f, 0.f, 0.f, 0.f};
#pragma unroll
        for (int ks = 0; ks < 2; ++ks) {
            bf16x8 WbH[4], WbL[4];
#pragma unroll
            for (int jt = 0; jt < 4; ++jt) {
                const int off = FIDX(ks, jt, qd, m);
                WbH[jt] = *(const bf16x8*)(WBh + off);
                WbL[jt] = *(const bf16x8*)(WBl + off);
            }
            const bf16x8 A = ks ? Ah1 : Ah0;
#pragma unroll
            for (int jt = 0; jt < 4; ++jt) {
                accQ[jt] = __builtin_amdgcn_mfma_f32_16x16x32_bf16(A, WbH[jt], accQ[jt], 0, 0, 0);
                accQ[jt] = __builtin_amdgcn_mfma_f32_16x16x32_bf16(A, WbL[jt], accQ[jt], 0, 0, 0);
            }
        }
#pragma unroll
        for (int r = 0; r < 4; ++r) {
            const int row = qd * 4 + r;
            if (row < CHUNK) {
#pragma unroll
                for (int jt = 0; jt < 4; ++jt)
                    qt[wave][row * QSTRIDE + jt * 16 + m] = accQ[jt][r] + bmsgC[jt];
            }
        }
    }

    // ---- W_gcn B-frags + scalar bias ----
    bf16x8 Gh[2][4];
#pragma unroll
    for (int ks = 0; ks < 2; ++ks)
#pragma unroll
        for (int jt = 0; jt < 4; ++jt)
            Gh[ks][jt] = *(const bf16x8*)(WGh + FIDX(ks, jt, qd, m));

    float bias_gcn[4];
#pragma unroll
    for (int jt = 0; jt < 4; ++jt) bias_gcn[jt] = b_gcn[jt * 16 + m];

    // ---- chunk edge range ----
    const int rpv = row_ptr[l0 + min(lane, nl)];
#define RP(i) __shfl(rpv, (i), 64)
    const int eb = __builtin_amdgcn_readfirstlane(RP(0));
    const int ee = __builtin_amdgcn_readfirstlane(RP(nl));
    if (eb >= ee) {                       // whole chunk empty
        for (int i = 0; i < nl; ++i) {
            Sb[(size_t)(l0 + i) * D + lane] = 0;
            if (do_p) Pout[(size_t)(l0 + i) * D + lane] = 0;  // P of zero S = 0
        }
        return;
    }
    const int ntiles = (ee - eb + 15) >> 4;

    // ---- prologue: sv 2 deep, p current ----
    int sv0 = sfirst[eb + m];
    int sv1 = sfirst[eb + 16 + m];
    bf16x8 p00, p01;
    {
        const unsigned short* Pr = P + (size_t)(sv0 & 0xFFFFF) * D;
        p00 = *(const bf16x8*)(Pr + qd * 8);
        p01 = *(const bf16x8*)(Pr + 32 + qd * 8);
    }

    int bcur = 0;
    float rsum[4] = {0.f, 0.f, 0.f, 0.f};
    int eo = eb;

    for (int t = 0; t < ntiles; ++t, eo += 16) {
        // sv for t+2
        const int sv2 = sfirst[eo + 32 + m];
        // p for t+1
        const unsigned short* Pr1 = P + (size_t)(sv1 & 0xFFFFF) * D;
        const bf16x8 p10 = *(const bf16x8*)(Pr1 + qd * 8);
        const bf16x8 p11 = *(const bf16x8*)(Pr1 + 32 + qd * 8);

        // per-lane link id for this tile's gather column (edge eo+m)
        const bool valid = (eo + m < ee);
        const int limv = valid ? ((sv0 >> 20) & 7) : 8;
        const int qoff = (valid ? ((sv0 >> 20) & 7) : 0) * QSTRIDE + qd * 8;

        // Q re-read (per-lane address; same-li lanes broadcast)
        float qb[16];
        *(float4*)&qb[0]  = *(const float4*)&qt[wave][qoff];
        *(float4*)&qb[4]  = *(const float4*)&qt[wave][qoff + 4];
        *(float4*)&qb[8]  = *(const float4*)&qt[wave][qoff + 32];
        *(float4*)&qb[12] = *(const float4*)&qt[wave][qoff + 36];

        // selu + pack
        float msgA[8];
#pragma unroll
        for (int i = 0; i < 8; ++i)
            msgA[i] = selu_x2(bf2f(p00[i]) + qb[i]);
        const bf16x8 Ah0 = pack8(msgA);
        float msgB[8];
#pragma unroll
        for (int i = 0; i < 8; ++i)
            msgB[i] = selu_x2(bf2f(p01[i]) + qb[8 + i]);
        const bf16x8 Ah1 = pack8(msgB);

        f32x4 acc[4];
#pragma unroll
        for (int jt = 0; jt < 4; ++jt) {
            const float b = bias_gcn[jt];
            acc[jt] = (f32x4){b, b, b, b};
            acc[jt] = __builtin_amdgcn_mfma_f32_16x16x32_bf16(Ah0, Gh[0][jt], acc[jt], 0, 0, 0);
            acc[jt] = __builtin_amdgcn_mfma_f32_16x16x32_bf16(Ah1, Gh[1][jt], acc[jt], 0, 0, 0);
        }

        // link ids of this lane's rows (rows qd*4+r; li of edge eo+j is in lane j)
        const int lr0 = __shfl(limv, qd * 4 + 0, 64);
        const int lr1 = __shfl(limv, qd * 4 + 1, 64);
        const int lr2 = __shfl(limv, qd * 4 + 2, 64);
        const int lr3 = __shfl(limv, qd * 4 + 3, 64);

        // segmented accumulate / finish loop (wave-uniform control)
        while (true) {
            const int b0 = bcur;
#pragma unroll
            for (int jt = 0; jt < 4; ++jt) {
                rsum[jt] += fmaxf((lr0 == b0) ? acc[jt][0] : 0.0f, 0.0f);
                rsum[jt] += fmaxf((lr1 == b0) ? acc[jt][1] : 0.0f, 0.0f);
                rsum[jt] += fmaxf((lr2 == b0) ? acc[jt][2] : 0.0f, 0.0f);
                rsum[jt] += fmaxf((lr3 == b0) ? acc[jt][3] : 0.0f, 0.0f);
            }
            if (bcur < nl && RP(bcur + 1) <= eo + 16) {   // link b0 ends here
#pragma unroll
                for (int jt = 0; jt < 4; ++jt) {
                    rsum[jt] += __shfl_xor(rsum[jt], 16, 64);
                    rsum[jt] += __shfl_xor(rsum[jt], 32, 64);
                }
                const float outv = (qd == 0) ? rsum[0] : (qd == 1) ? rsum[1]
                                 : (qd == 2) ? rsum[2] : rsum[3];
                const unsigned short sbv = (unsigned short)f2bf_rtne(outv);
                Sb[(size_t)(l0 + bcur) * D + lane] = sbv;
                srow[wave][bcur * SSTRIDE + lane] = sbv;
#pragma unroll
                for (int jt = 0; jt < 4; ++jt) rsum[jt] = 0.0f;
                ++bcur;
                if (bcur >= nl) break;
            } else {
                break;
            }
        }

        sv0 = sv1; sv1 = sv2;
        p00 = p10; p01 = p11;
    }

    // defensive: any link not closed (should not happen) gets zeros
    while (bcur < nl) {
        Sb[(size_t)(l0 + bcur) * D + lane] = 0;
        srow[wave][bcur * SSTRIDE + lane] = 0;
        ++bcur;
    }

    // ---- fused P(t+1) for this chunk from LDS-stashed S rows ----
    if (do_p) {
        const bf16x8 z = (bf16x8){0, 0, 0, 0, 0, 0, 0, 0};
        bf16x8 Sa0 = z, Sa1 = z;
        if (m < nl) {
            Sa0 = *(const bf16x8*)&srow[wave][m * SSTRIDE + qd * 8];
            Sa1 = *(const bf16x8*)&srow[wave][m * SSTRIDE + 32 + qd * 8];
        }
        f32x4 accP[4];
#pragma unroll
        for (int jt = 0; jt < 4; ++jt) accP[jt] = (f32x4){0.f, 0.f, 0.f, 0.f};
#pragma unroll
        for (int ks = 0; ks < 2; ++ks) {
            const bf16x8 A = ks ? Sa1 : Sa0;
#pragma unroll
            for (int jt = 0; jt < 4; ++jt) {
                const int off = FIDX(ks, jt, qd, m);
                const bf16x8 BH = *(const bf16x8*)(WAh + off);
                const bf16x8 BL = *(const bf16x8*)(WAl + off);
                accP[jt] = __builtin_amdgcn_mfma_f32_16x16x32_bf16(A, BH, accP[jt], 0, 0, 0);
                accP[jt] = __builtin_amdgcn_mfma_f32_16x16x32_bf16(A, BL, accP[jt], 0, 0, 0);
            }
        }
#pragma unroll
        for (int r = 0; r < 4; ++r) {
            const int lr = qd * 4 + r;
            if (lr < nl) {
#pragma unroll
                for (int jt = 0; jt < 4; ++jt)
                    Pout[(size_t)(l0 + lr) * D + jt * 16 + m] =
                        (unsigned short)f2bf_rtne(accP[jt][r]);
            }
        }
    }
#undef RP
}

// ---------------- readout: parallel segment-sum (bf16 S) + tiny MLP ---------
__global__ __launch_bounds__(256) void gsum8_kernel(
    const unsigned short* __restrict__ Sb, const int* __restrict__ grow,
    float* __restrict__ gemb)
{
    __shared__ float red[4][64];
    const int g = blockIdx.x >> 3;
    const int slice = blockIdx.x & 7;
    const int slot = threadIdx.x >> 6;
    const int j = threadIdx.x & 63;
    const int ls = grow[g], le = grow[g + 1];
    float acc = 0.0f;
    for (int l = ls + slice * 4 + slot; l < le; l += 32)
        acc += bf2f((short)Sb[(size_t)l * D + j]);
    red[slot][j] = acc;
    __syncthreads();
    if (slot == 0)
        atomicAdd(&gemb[g * D + j], red[0][j] + red[1][j] + red[2][j] + red[3][j]);
}

__global__ __launch_bounds__(256) void mlp_kernel(
    const float* __restrict__ gemb,
    const float* __restrict__ W_r1, const float* __restrict__ b_r1,
    const float* __restrict__ W_r2, const float* __restrict__ b_r2,
    const float* __restrict__ W_r3, const float* __restrict__ b_r3,
    float* __restrict__ out)
{
    __shared__ float gl[64];
    __shared__ float row1[RU];
    __shared__ float row2[RU];
    __shared__ float fin[4];
    const int g = blockIdx.x;
    const int tid = threadIdx.x;
    const int slot = tid >> 6;
    const int lane = tid & 63;

    if (tid < 64) gl[tid] = gemb[g * D + tid];
    __syncthreads();

    float a1 = b_r1[tid];
#pragma unroll 8
    for (int k = 0; k < 64; ++k) a1 += gl[k] * W_r1[k * RU + tid];
    row1[tid] = selu_f(a1);
    __syncthreads();

    float a2 = b_r2[tid];
#pragma unroll 8
    for (int k = 0; k < RU; ++k) a2 += row1[k] * W_r2[k * RU + tid];
    row2[tid] = selu_f(a2);
    __syncthreads();

    float p = row2[tid] * W_r3[tid];
#pragma unroll
    for (int off = 32; off >= 1; off >>= 1)
        p += __shfl_down(p, off, 64);
    if (lane == 0) fin[slot] = p;
    __syncthreads();
    if (tid == 0)
        out[g] = fin[0] + fin[1] + fin[2] + fin[3] + b_r3[0];
}

extern "C" void kernel_launch(void* const* d_in, const int* in_sizes, int n_in,
                              void* d_out, int out_size, void* d_ws, size_t ws_size,
                              hipStream_t stream)
{
    const float* states_action = (const float*)d_in[0];
    const float* W_msg = (const float*)d_in[1];
    const float* b_msg = (const float*)d_in[2];
    const float* W_gcn = (const float*)d_in[3];
    const float* b_gcn = (const float*)d_in[4];
    const float* W_r1 = (const float*)d_in[5];
    const float* b_r1 = (const float*)d_in[6];
    const float* W_r2 = (const float*)d_in[7];
    const float* b_r2 = (const float*)d_in[8];
    const float* W_r3 = (const float*)d_in[9];
    const float* b_r3 = (const float*)d_in[10];
    const int* gid = (const int*)d_in[11];
    const int* first = (const int*)d_in[12];
    const int* second = (const int*)d_in[13];

    const int n_links = in_sizes[0] / D;     // 100000
    const int n_edges = in_sizes[12];        // 1600000
    const int G = out_size;                  // 256
    const int nbins = (n_links + 127) >> BIN_SHIFT;   // 782

    char* ws2 = (char*)d_ws;
    auto alloc = [&](size_t bytes) {
        char* p = ws2; ws2 += (bytes + 63) & ~(size_t)63; return p;
    };
    unsigned short* Sb = (unsigned short*)alloc((size_t)n_links * D * 2);       // 12.8 MB
    unsigned short* Pb = (unsigned short*)alloc((size_t)n_links * D * 2);       // 12.8 MB
    float* gemb = (float*)alloc((size_t)G * D * sizeof(float));
    int* row_ptr = (int*)alloc((size_t)(n_links + 1) * sizeof(int));
    int* grow = (int*)alloc((size_t)(G + 1) * sizeof(int));
    unsigned* tmp = (unsigned*)alloc((size_t)n_edges * sizeof(unsigned));       // 6.4 MB
    int* sfirst = (int*)alloc((size_t)(n_edges + 64) * sizeof(int));            // 6.4 MB (ghist aliases head)
    unsigned short* WAh = (unsigned short*)alloc(4096 * 2);
    unsigned short* WAl = (unsigned short*)alloc(4096 * 2);
    unsigned short* WBh = (unsigned short*)alloc(4096 * 2);
    unsigned short* WBl = (unsigned short*)alloc(4096 * 2);
    unsigned short* WGh = (unsigned short*)alloc(4096 * 2);
    int* btot = (int*)alloc((size_t)nbins * sizeof(int));
    // ghist aliases sfirst: ghist live histA..scatterC; sfirst written only by
    // binsortD (strictly after scatterC). nbins*NSB = 200192 ints <= 6.4 MB.
    int* ghist = (int*)sfirst;

    // ---- optional P ping-pong buffer for fused P-tail (runtime ws gate) ----
    const size_t used = (size_t)(ws2 - (char*)d_ws);
    const size_t p2bytes = (size_t)n_links * D * 2;
    const bool pfuse = (used + p2bytes + 64 <= ws_size);
    unsigned short* Pb2 = pfuse ? (unsigned short*)alloc(p2bytes) : Pb;

    // ---- input conversion + weight prep + atomic-free CSR build ----
    hipMemsetAsync(gemb, 0, (size_t)G * D * sizeof(float), stream);
    s2bf_kernel<<<1024, 256, 0, stream>>>(states_action, Sb, n_links * D / 4);
    wprep_kernel<<<16, 256, 0, stream>>>(W_msg, W_gcn, WAh, WAl, WBh, WBl, WGh);
    histA_kernel<<<NSB, 256, 0, stream>>>(second, ghist, n_edges, nbins);
    sumbins_kernel<<<nbins, 64, 0, stream>>>(ghist, btot, nbins);
    scanS_kernel<<<1, 1024, 0, stream>>>(btot, nbins);
    scatterC_kernel<<<NSB, 256, 0, stream>>>(first, second, ghist, btot, tmp,
                                             n_edges, nbins);
    binsortD_kernel<<<nbins, 256, 0, stream>>>(tmp, btot, sfirst, row_ptr,
                                               n_edges, n_links, nbins);
    growfind_kernel<<<2, 256, 0, stream>>>(gid, grow, n_links, G);

    // ---- T = 4 message-passing iterations (state lives in Sb, bf16) ----
    const int edge_blocks = (n_links + 4 * CHUNK - 1) / (4 * CHUNK);  // 3125
    p_mfma_kernel<<<1024, 256, 0, stream>>>(Sb, WAh, WAl, Pb, n_links);
    if (pfuse) {
        unsigned short* Pc = Pb;
        unsigned short* Pn = Pb2;
        for (int t = 0; t < 4; ++t) {
            edge_link_kernel<<<edge_blocks, 256, 0, stream>>>(
                Sb, Pc, sfirst, row_ptr, b_msg, WBh, WBl, WGh, b_gcn,
                WAh, WAl, Pn, (t < 3) ? 1 : 0, n_links);
            unsigned short* sw = Pc; Pc = Pn; Pn = sw;
        }
    } else {
        for (int t = 0; t < 4; ++t) {
            if (t) p_mfma_kernel<<<1024, 256, 0, stream>>>(Sb, WAh, WAl, Pb, n_links);
            edge_link_kernel<<<edge_blocks, 256, 0, stream>>>(
                Sb, Pb, sfirst, row_ptr, b_msg, WBh, WBl, WGh, b_gcn,
                WAh, WAl, Pb, 0, n_links);
        }
    }

    // ---- readout ----
    gsum8_kernel<<<G * 8, 256, 0, stream>>>(Sb, grow, gemb);
    mlp_kernel<<<G, 256, 0, stream>>>(gemb, W_r1, b_r1, W_r2, b_r2,
                                      W_r3, b_r3, (float*)d_out);
}